// Round 1
// baseline (38258.456 us; speedup 1.0000x reference)
//
#include <hip/hip_runtime.h>
#include <math.h>

#define Hd     256
#define NLAY   6
#define NST    64
#define DCONVK 4
#define DINv   512
#define NHEADS 8
#define CONVDv 640   // DIN + 2N
#define PROJv  1160  // 2*DIN + 2*N + HEADS
#define TCH    16    // tokens per chunk
#define BLK    512

__device__ __forceinline__ float siluf(float v) { return v / (1.0f + expf(-v)); }

// One block per sequence. Sequence rows are contiguous in xin: row = s*L + t.
// TMODE=true (time pass): output row = ((s>>6)*512 + t)*64 + (s&63)  (the swapaxes transpose)
// TMODE=false (band pass): output row = input row.
template<bool TMODE>
__global__ __launch_bounds__(BLK)
void mamba_pass(const float* __restrict__ xin, float* __restrict__ xout,
                const float* __restrict__ nw,   const float* __restrict__ Win,
                const float* __restrict__ cwp,  const float* __restrict__ cbp,
                const float* __restrict__ dtbp, const float* __restrict__ alogp,
                const float* __restrict__ Dp,   const float* __restrict__ gnp,
                const float* __restrict__ Woutp, int L)
{
    __shared__ __align__(16) float sBuf[TCH][648];   // xBC(640)+dt(8) per token; later y/gy in cols 0..511
    __shared__ __align__(16) float sXnT[Hd][TCH];    // normalized input, transposed [r][tok]
    __shared__ float sDt[TCH][NHEADS];
    __shared__ float sDA[TCH][NHEADS];
    __shared__ float sRstd[TCH];

    const int tid = threadIdx.x;
    const int s   = blockIdx.x;

    // ---- per-sequence persistent state ----
    float c0w[DCONVK], c1w[DCONVK];
    float c0b = cbp[tid], c1b = 0.f;
    const bool hasCh1 = (tid < CONVDv - DINv);   // tid < 128
#pragma unroll
    for (int k = 0; k < DCONVK; k++) c0w[k] = cwp[k * CONVDv + tid];
    if (hasCh1) {
        c1b = cbp[DINv + tid];
#pragma unroll
        for (int k = 0; k < DCONVK; k++) c1w[k] = cwp[k * CONVDv + DINv + tid];
    }
    float w0a = 0.f, w0b = 0.f, w0c = 0.f;   // rolling conv windows (zero padding)
    float w1a = 0.f, w1b = 0.f, w1c = 0.f;

    const int head = tid >> 6;               // scan: thread owns (head, p)
    const float Dh = Dp[head];
    float hst[NST];
#pragma unroll
    for (int n = 0; n < NST; n++) hst[n] = 0.f;

    const int tok    = tid >> 5;             // 0..15 (P0/P5 mapping)
    const int lane32 = tid & 31;

    for (int cbase = 0; cbase < L; cbase += TCH) {
        // ---------- P0: load x chunk + input rmsnorm -> sXnT ----------
        {
            const int t = cbase + tok;
            const float* xr = xin + ((size_t)s * L + t) * Hd + lane32 * 8;
            float4 a = ((const float4*)xr)[0];
            float4 b = ((const float4*)xr)[1];
            float ss = a.x*a.x + a.y*a.y + a.z*a.z + a.w*a.w
                     + b.x*b.x + b.y*b.y + b.z*b.z + b.w*b.w;
#pragma unroll
            for (int m = 16; m >= 1; m >>= 1) ss += __shfl_xor(ss, m, 32);
            const float rstd = rsqrtf(ss * (1.0f / Hd) + 1e-6f);
            const float* nwr = nw + lane32 * 8;
            float xv[8] = {a.x, a.y, a.z, a.w, b.x, b.y, b.z, b.w};
#pragma unroll
            for (int j = 0; j < 8; j++)
                sXnT[lane32 * 8 + j][tok] = xv[j] * rstd * nwr[j];
        }
        __syncthreads();

        // ---------- P1: proj cols 512..1159 (xBC + dt) ----------
        {
            float acc0[TCH], acc1[TCH];
#pragma unroll
            for (int i = 0; i < TCH; i++) { acc0[i] = 0.f; acc1[i] = 0.f; }
            const bool c2 = (tid < PROJv - 1024);   // tid < 136
#pragma unroll 4
            for (int r = 0; r < Hd; r++) {
                const float* wr = Win + (size_t)r * PROJv;
                const float wv0 = wr[DINv + tid];
                const float4* xp = (const float4*)&sXnT[r][0];
                float4 x0 = xp[0], x1 = xp[1], x2 = xp[2], x3 = xp[3];
                acc0[0]  = fmaf(x0.x, wv0, acc0[0]);  acc0[1]  = fmaf(x0.y, wv0, acc0[1]);
                acc0[2]  = fmaf(x0.z, wv0, acc0[2]);  acc0[3]  = fmaf(x0.w, wv0, acc0[3]);
                acc0[4]  = fmaf(x1.x, wv0, acc0[4]);  acc0[5]  = fmaf(x1.y, wv0, acc0[5]);
                acc0[6]  = fmaf(x1.z, wv0, acc0[6]);  acc0[7]  = fmaf(x1.w, wv0, acc0[7]);
                acc0[8]  = fmaf(x2.x, wv0, acc0[8]);  acc0[9]  = fmaf(x2.y, wv0, acc0[9]);
                acc0[10] = fmaf(x2.z, wv0, acc0[10]); acc0[11] = fmaf(x2.w, wv0, acc0[11]);
                acc0[12] = fmaf(x3.x, wv0, acc0[12]); acc0[13] = fmaf(x3.y, wv0, acc0[13]);
                acc0[14] = fmaf(x3.z, wv0, acc0[14]); acc0[15] = fmaf(x3.w, wv0, acc0[15]);
                if (c2) {
                    const float wv1 = wr[1024 + tid];
                    acc1[0]  = fmaf(x0.x, wv1, acc1[0]);  acc1[1]  = fmaf(x0.y, wv1, acc1[1]);
                    acc1[2]  = fmaf(x0.z, wv1, acc1[2]);  acc1[3]  = fmaf(x0.w, wv1, acc1[3]);
                    acc1[4]  = fmaf(x1.x, wv1, acc1[4]);  acc1[5]  = fmaf(x1.y, wv1, acc1[5]);
                    acc1[6]  = fmaf(x1.z, wv1, acc1[6]);  acc1[7]  = fmaf(x1.w, wv1, acc1[7]);
                    acc1[8]  = fmaf(x2.x, wv1, acc1[8]);  acc1[9]  = fmaf(x2.y, wv1, acc1[9]);
                    acc1[10] = fmaf(x2.z, wv1, acc1[10]); acc1[11] = fmaf(x2.w, wv1, acc1[11]);
                    acc1[12] = fmaf(x3.x, wv1, acc1[12]); acc1[13] = fmaf(x3.y, wv1, acc1[13]);
                    acc1[14] = fmaf(x3.z, wv1, acc1[14]); acc1[15] = fmaf(x3.w, wv1, acc1[15]);
                }
            }
#pragma unroll
            for (int i = 0; i < TCH; i++) sBuf[i][tid] = acc0[i];
            if (c2) {
#pragma unroll
                for (int i = 0; i < TCH; i++) sBuf[i][DINv + tid] = acc1[i];
            }
        }
        __syncthreads();

        // ---------- P2: causal conv4 + silu (in place, cols 0..639) ; dt -> softplus/dA ----------
        {
#pragma unroll
            for (int tt = 0; tt < TCH; tt++) {
                float raw = sBuf[tt][tid];
                float v = c0b + c0w[0]*w0a + c0w[1]*w0b + c0w[2]*w0c + c0w[3]*raw;
                w0a = w0b; w0b = w0c; w0c = raw;
                sBuf[tt][tid] = siluf(v);
                if (hasCh1) {
                    float raw1 = sBuf[tt][DINv + tid];
                    float v1 = c1b + c1w[0]*w1a + c1w[1]*w1b + c1w[2]*w1c + c1w[3]*raw1;
                    w1a = w1b; w1b = w1c; w1c = raw1;
                    sBuf[tt][DINv + tid] = siluf(v1);
                }
            }
            if (tid < TCH * NHEADS) {
                const int tk = tid >> 3, hh = tid & 7;
                float dtraw = sBuf[tk][CONVDv + hh] + dtbp[hh];
                float sp = (dtraw > 20.f) ? dtraw : log1pf(expf(dtraw));
                sDt[tk][hh] = sp;
                sDA[tk][hh] = expf(-expf(alogp[hh]) * sp);
            }
        }
        __syncthreads();

        // ---------- P4: recurrent scan; write y into own xs column ----------
        {
#pragma unroll 1
            for (int tt = 0; tt < TCH; tt++) {
                const float xh  = sBuf[tt][tid];
                const float dtv = sDt[tt][head];
                const float dAv = sDA[tt][head];
                const float xdt = xh * dtv;
                const float4* B4 = (const float4*)&sBuf[tt][DINv];
                const float4* C4 = (const float4*)&sBuf[tt][DINv + 64];
                float y0 = 0.f, y1 = 0.f, y2 = 0.f, y3 = 0.f;
#pragma unroll
                for (int q = 0; q < 16; q++) {
                    float4 bb = B4[q], cc = C4[q];
                    float h0 = fmaf(dAv, hst[4*q+0], xdt * bb.x);
                    float h1 = fmaf(dAv, hst[4*q+1], xdt * bb.y);
                    float h2 = fmaf(dAv, hst[4*q+2], xdt * bb.z);
                    float h3 = fmaf(dAv, hst[4*q+3], xdt * bb.w);
                    hst[4*q+0] = h0; hst[4*q+1] = h1; hst[4*q+2] = h2; hst[4*q+3] = h3;
                    y0 = fmaf(h0, cc.x, y0); y1 = fmaf(h1, cc.y, y1);
                    y2 = fmaf(h2, cc.z, y2); y3 = fmaf(h3, cc.w, y3);
                }
                sBuf[tt][tid] = fmaf(Dh, xh, (y0 + y1) + (y2 + y3));
            }
        }
        // no barrier needed: each thread only touched its own column (B/C cols untouched)

        // ---------- P3: z projection (cols 0..511) + silu gate (in place) ----------
        {
            float zacc[TCH];
#pragma unroll
            for (int i = 0; i < TCH; i++) zacc[i] = 0.f;
#pragma unroll 4
            for (int r = 0; r < Hd; r++) {
                const float wv = Win[(size_t)r * PROJv + tid];
                const float4* xp = (const float4*)&sXnT[r][0];
                float4 x0 = xp[0], x1 = xp[1], x2 = xp[2], x3 = xp[3];
                zacc[0]  = fmaf(x0.x, wv, zacc[0]);  zacc[1]  = fmaf(x0.y, wv, zacc[1]);
                zacc[2]  = fmaf(x0.z, wv, zacc[2]);  zacc[3]  = fmaf(x0.w, wv, zacc[3]);
                zacc[4]  = fmaf(x1.x, wv, zacc[4]);  zacc[5]  = fmaf(x1.y, wv, zacc[5]);
                zacc[6]  = fmaf(x1.z, wv, zacc[6]);  zacc[7]  = fmaf(x1.w, wv, zacc[7]);
                zacc[8]  = fmaf(x2.x, wv, zacc[8]);  zacc[9]  = fmaf(x2.y, wv, zacc[9]);
                zacc[10] = fmaf(x2.z, wv, zacc[10]); zacc[11] = fmaf(x2.w, wv, zacc[11]);
                zacc[12] = fmaf(x3.x, wv, zacc[12]); zacc[13] = fmaf(x3.y, wv, zacc[13]);
                zacc[14] = fmaf(x3.z, wv, zacc[14]); zacc[15] = fmaf(x3.w, wv, zacc[15]);
            }
#pragma unroll
            for (int i = 0; i < TCH; i++) {
                const float z = zacc[i];
                sBuf[i][tid] = sBuf[i][tid] * siluf(z);   // own column, no barrier needed
            }
        }
        __syncthreads();

        // ---------- P5: rmsnorm of gated y (512 per token) ----------
        {
            const float4* rp = (const float4*)&sBuf[tok][lane32 * 16];
            float4 a = rp[0], b = rp[1], c = rp[2], d = rp[3];
            float ss = a.x*a.x + a.y*a.y + a.z*a.z + a.w*a.w
                     + b.x*b.x + b.y*b.y + b.z*b.z + b.w*b.w
                     + c.x*c.x + c.y*c.y + c.z*c.z + c.w*c.w
                     + d.x*d.x + d.y*d.y + d.z*d.z + d.w*d.w;
#pragma unroll
            for (int m = 16; m >= 1; m >>= 1) ss += __shfl_xor(ss, m, 32);
            if (lane32 == 0) sRstd[tok] = rsqrtf(ss * (1.0f / DINv) + 1e-6f);
        }
        __syncthreads();

        // ---------- P6: out projection (512x256), residual, store ----------
        {
            const int c    = tid & 255;
            const int half = tid >> 8;
            float oacc[TCH];
#pragma unroll
            for (int i = 0; i < TCH; i++) oacc[i] = 0.f;
            const int rb = half * 256;
#pragma unroll 4
            for (int r = rb; r < rb + 256; r++) {
                const float wg = Woutp[(size_t)r * Hd + c] * gnp[r];
#pragma unroll
                for (int i = 0; i < TCH; i++) oacc[i] = fmaf(sBuf[i][r], wg, oacc[i]);
            }
            if (half == 1) {
#pragma unroll
                for (int i = 0; i < TCH; i++) sXnT[c][i] = oacc[i];  // sXnT reused as scratch
            }
            __syncthreads();
            if (half == 0) {
#pragma unroll
                for (int i = 0; i < TCH; i++) {
                    const int t = cbase + i;
                    const size_t inrow = (size_t)s * L + t;
                    size_t orow;
                    if (TMODE) orow = ((size_t)((s >> 6) * 512 + t)) * 64 + (s & 63);
                    else       orow = inrow;
                    const float resid = xin[inrow * Hd + c];
                    xout[orow * Hd + c] = fmaf(oacc[i] + sXnT[c][i], sRstd[i], resid);
                }
            }
        }
        __syncthreads();   // protect sBuf/sXnT reuse next chunk
    }
}

extern "C" void kernel_launch(void* const* d_in, const int* in_sizes, int n_in,
                              void* d_out, int out_size, void* d_ws, size_t ws_size,
                              hipStream_t stream) {
    const float* x      = (const float*)d_in[0];
    const float* t_norm = (const float*)d_in[1];
    const float* t_Win  = (const float*)d_in[2];
    const float* t_cw   = (const float*)d_in[3];
    const float* t_cb   = (const float*)d_in[4];
    const float* t_dtb  = (const float*)d_in[5];
    const float* t_Alog = (const float*)d_in[6];
    const float* t_D    = (const float*)d_in[7];
    const float* t_gn   = (const float*)d_in[8];
    const float* t_Wout = (const float*)d_in[9];
    const float* b_norm = (const float*)d_in[10];
    const float* b_Win  = (const float*)d_in[11];
    const float* b_cw   = (const float*)d_in[12];
    const float* b_cb   = (const float*)d_in[13];
    const float* b_dtb  = (const float*)d_in[14];
    const float* b_Alog = (const float*)d_in[15];
    const float* b_D    = (const float*)d_in[16];
    const float* b_gn   = (const float*)d_in[17];
    const float* b_Wout = (const float*)d_in[18];

    float* out = (float*)d_out;
    float* ws  = (float*)d_ws;   // 64 MB ping-pong buffer (canonical layout)

    for (int i = 0; i < NLAY; i++) {
        const float* src = (i == 0) ? x : out;
        // time pass: 128 sequences of L=512; writes transposed into ws
        mamba_pass<true><<<dim3(128), dim3(BLK), 0, stream>>>(
            src, ws,
            t_norm + i * Hd, t_Win + (size_t)i * Hd * PROJv,
            t_cw + i * DCONVK * CONVDv, t_cb + i * CONVDv,
            t_dtb + i * NHEADS, t_Alog + i * NHEADS, t_D + i * NHEADS,
            t_gn + i * DINv, t_Wout + (size_t)i * DINv * Hd, 512);
        // band pass: 1024 sequences of L=64; identity layout ws -> out
        mamba_pass<false><<<dim3(1024), dim3(BLK), 0, stream>>>(
            ws, out,
            b_norm + i * Hd, b_Win + (size_t)i * Hd * PROJv,
            b_cw + i * DCONVK * CONVDv, b_cb + i * CONVDv,
            b_dtb + i * NHEADS, b_Alog + i * NHEADS, b_D + i * NHEADS,
            b_gn + i * DINv, b_Wout + (size_t)i * DINv * Hd, 64);
    }
}

// Round 2
// 18917.387 us; speedup vs baseline: 2.0224x; 2.0224x over previous
//
#include <hip/hip_runtime.h>
#include <math.h>

#define NLAY   6
#define Hd     256
#define DINv   512
#define NHEADS 8
#define CONVDv 640
#define PROJv  1160   // 2*DIN + 2*N + HEADS
#define NTOK   65536  // tokens per pass (both directions)

__device__ __forceinline__ float siluf(float v) { return v / (1.0f + expf(-v)); }
__device__ __forceinline__ float bflo(unsigned u) { return __uint_as_float(u << 16); }
__device__ __forceinline__ float bfhi(unsigned u) { return __uint_as_float(u & 0xffff0000u); }
__device__ __forceinline__ unsigned short f2b(float f) {  // RNE fp32->bf16
    unsigned u = __float_as_uint(f);
    return (unsigned short)((u + 0x7fffu + ((u >> 16) & 1u)) >> 16);
}
__device__ __forceinline__ float b2f(unsigned short s) { return __uint_as_float(((unsigned)s) << 16); }

// ---------------- K1: rmsnorm(x) @ Win -> zxbcdt (bf16) ----------------
// grid 4096 x 512 threads, 16 tokens/block. Token rows are pure row ops.
__global__ __launch_bounds__(512)
void k1_proj(const float* __restrict__ src, unsigned short* __restrict__ zx,
             const float* __restrict__ nw, const float* __restrict__ Win)
{
    __shared__ __align__(16) float sX[Hd][16];   // normalized x, transposed [r][tok]
    const int tid = threadIdx.x;
    const int R0  = blockIdx.x * 16;

    // P0: load 16x256 tile + rmsnorm
    {
        const int tok = tid >> 5, lane = tid & 31;
        const float* xr = src + ((size_t)(R0 + tok)) * Hd + lane * 8;
        float4 a = ((const float4*)xr)[0];
        float4 b = ((const float4*)xr)[1];
        float ss = a.x*a.x + a.y*a.y + a.z*a.z + a.w*a.w
                 + b.x*b.x + b.y*b.y + b.z*b.z + b.w*b.w;
#pragma unroll
        for (int m = 16; m >= 1; m >>= 1) ss += __shfl_xor(ss, m, 32);
        const float rstd = rsqrtf(ss * (1.0f / Hd) + 1e-6f);
        const float* nwr = nw + lane * 8;
        float xv[8] = {a.x, a.y, a.z, a.w, b.x, b.y, b.z, b.w};
#pragma unroll
        for (int j = 0; j < 8; j++)
            sX[lane * 8 + j][tok] = xv[j] * rstd * nwr[j];
    }
    __syncthreads();

    // GEMM 16 x 256 x 1160; thread -> cols {tid, tid+512, tid+1024(if<136)}
    float a0[16], a1[16], a2[16];
#pragma unroll
    for (int i = 0; i < 16; i++) { a0[i] = 0.f; a1[i] = 0.f; a2[i] = 0.f; }
    const bool c2 = (tid < PROJv - 1024);
    const float* wp = Win + tid;
#pragma unroll 2
    for (int r = 0; r < Hd; r++) {
        const float w0 = wp[0];
        const float w1 = wp[512];
        const float4* xp = (const float4*)&sX[r][0];
        float4 xq0 = xp[0], xq1 = xp[1], xq2 = xp[2], xq3 = xp[3];
        float xs[16] = {xq0.x,xq0.y,xq0.z,xq0.w, xq1.x,xq1.y,xq1.z,xq1.w,
                        xq2.x,xq2.y,xq2.z,xq2.w, xq3.x,xq3.y,xq3.z,xq3.w};
#pragma unroll
        for (int i = 0; i < 16; i++) {
            a0[i] = fmaf(xs[i], w0, a0[i]);
            a1[i] = fmaf(xs[i], w1, a1[i]);
        }
        if (c2) {
            const float w2 = wp[1024];
#pragma unroll
            for (int i = 0; i < 16; i++) a2[i] = fmaf(xs[i], w2, a2[i]);
        }
        wp += PROJv;
    }
    unsigned short* zr = zx + (size_t)R0 * PROJv;
#pragma unroll
    for (int i = 0; i < 16; i++) {
        zr[(size_t)i * PROJv + tid]       = f2b(a0[i]);
        zr[(size_t)i * PROJv + 512 + tid] = f2b(a1[i]);
        if (c2) zr[(size_t)i * PROJv + 1024 + tid] = f2b(a2[i]);
    }
}

// ---------------- K2: conv4+silu, softplus/dA, recurrent scan, silu(z) gate ----------------
// grid (S, 8 heads), 64 threads (1 wave). Thread = p. h[64] state in VGPRs.
// Writes gated y IN PLACE over z columns [head*64 .. head*64+63] of zx.
__global__ __launch_bounds__(64)
void k2_scan(unsigned short* __restrict__ zx,
             const float* __restrict__ cwp, const float* __restrict__ cbp,
             const float* __restrict__ dtbp, const float* __restrict__ alogp,
             const float* __restrict__ Dp, int L)
{
    __shared__ __align__(16) float sB[64];
    __shared__ __align__(16) float sC[64];
    const int p    = threadIdx.x;
    const int head = blockIdx.y;
    const int s    = blockIdx.x;

    const int chx = head * 64 + p;       // xs channel
    // conv weights: cw[k][CONVD]
    float cx0 = cwp[0*CONVDv + chx], cx1 = cwp[1*CONVDv + chx],
          cx2 = cwp[2*CONVDv + chx], cx3 = cwp[3*CONVDv + chx];
    float cb0_ = cbp[chx];
    float bb0 = cwp[0*CONVDv + 512 + p], bb1 = cwp[1*CONVDv + 512 + p],
          bb2 = cwp[2*CONVDv + 512 + p], bb3 = cwp[3*CONVDv + 512 + p];
    float cbb = cbp[512 + p];
    float cc0 = cwp[0*CONVDv + 576 + p], cc1 = cwp[1*CONVDv + 576 + p],
          cc2 = cwp[2*CONVDv + 576 + p], cc3 = cwp[3*CONVDv + 576 + p];
    float cbc = cbp[576 + p];

    const float dtb = dtbp[head];
    const float nA  = -expf(alogp[head]);
    const float Dh  = Dp[head];

    float wx0 = 0.f, wx1 = 0.f, wx2 = 0.f;   // conv windows
    float wb0 = 0.f, wb1 = 0.f, wb2 = 0.f;
    float wc0 = 0.f, wc1 = 0.f, wc2 = 0.f;

    float h[64];
#pragma unroll
    for (int n = 0; n < 64; n++) h[n] = 0.f;

    const size_t base = (size_t)s * L * PROJv;
    // prefetch token 0
    const unsigned short* rp = zx + base;
    float nx  = b2f(rp[512 + chx]);
    float nb  = b2f(rp[1024 + p]);
    float nc  = b2f(rp[1088 + p]);
    float ndt = b2f(rp[1152 + head]);
    float nz  = b2f(rp[chx]);

    for (int t = 0; t < L; t++) {
        const float xr = nx, br = nb, cr = nc, dtr = ndt, zv = nz;
        if (t + 1 < L) {  // prefetch next token (overlaps with compute below)
            const unsigned short* rn = zx + base + (size_t)(t + 1) * PROJv;
            nx  = b2f(rn[512 + chx]);
            nb  = b2f(rn[1024 + p]);
            nc  = b2f(rn[1088 + p]);
            ndt = b2f(rn[1152 + head]);
            nz  = b2f(rn[chx]);
        }
        const float dts = dtr + dtb;
        const float sp  = (dts > 20.f) ? dts : log1pf(expf(dts));
        const float dA  = expf(nA * sp);

        float xv = siluf(cb0_ + cx0*wx0 + cx1*wx1 + cx2*wx2 + cx3*xr);
        wx0 = wx1; wx1 = wx2; wx2 = xr;
        float bv = siluf(cbb + bb0*wb0 + bb1*wb1 + bb2*wb2 + bb3*br);
        wb0 = wb1; wb1 = wb2; wb2 = br;
        float cv = siluf(cbc + cc0*wc0 + cc1*wc1 + cc2*wc2 + cc3*cr);
        wc0 = wc1; wc1 = wc2; wc2 = cr;

        sB[p] = bv;
        sC[p] = cv;
        // single-wave block: DS ops are in-order per wave, no barrier needed
        const float xdt = xv * sp;
        float y = 0.f;
        const float4* B4 = (const float4*)sB;
        const float4* C4 = (const float4*)sC;
#pragma unroll
        for (int q = 0; q < 16; q++) {
            float4 bq = B4[q], cq = C4[q];
            h[4*q+0] = fmaf(dA, h[4*q+0], xdt * bq.x); y = fmaf(h[4*q+0], cq.x, y);
            h[4*q+1] = fmaf(dA, h[4*q+1], xdt * bq.y); y = fmaf(h[4*q+1], cq.y, y);
            h[4*q+2] = fmaf(dA, h[4*q+2], xdt * bq.z); y = fmaf(h[4*q+2], cq.z, y);
            h[4*q+3] = fmaf(dA, h[4*q+3], xdt * bq.w); y = fmaf(h[4*q+3], cq.w, y);
        }
        y = fmaf(Dh, xv, y);
        const float yg = y * siluf(zv);
        zx[base + (size_t)t * PROJv + chx] = f2b(yg);   // in place over z
    }
}

// ---------------- K3: rmsnorm(gated y) @ (gn*Wout) + residual, store (opt transpose) ----------------
// grid 4096 x 512 threads, 16 tokens/block. 4-way K split x 2 cols/thread.
template<bool TMODE>
__global__ __launch_bounds__(512)
void k3_out(const unsigned short* __restrict__ zx, const float* __restrict__ src,
            float* __restrict__ dst, const float* __restrict__ Woutp,
            const float* __restrict__ gnp)
{
    __shared__ __align__(16) float sY[DINv][16];   // 32 KB, reused as reduce buf
    __shared__ float sRstd[16];
    const int tid = threadIdx.x;
    const int R0  = blockIdx.x * 16;

    // Phase L: load gated-y tile (bf16, zx cols 0:512) -> sY transposed + rms
    {
        const int tok = tid >> 5, lane = tid & 31;
        const size_t row = (size_t)(R0 + tok);
        const uint4* yp = (const uint4*)(zx + row * PROJv);
        uint4 u0 = yp[lane * 2], u1 = yp[lane * 2 + 1];
        unsigned uu[8] = {u0.x, u0.y, u0.z, u0.w, u1.x, u1.y, u1.z, u1.w};
        float v[16];
#pragma unroll
        for (int k = 0; k < 8; k++) { v[2*k] = bflo(uu[k]); v[2*k+1] = bfhi(uu[k]); }
        float ss = 0.f;
#pragma unroll
        for (int j = 0; j < 16; j++) ss += v[j] * v[j];
#pragma unroll
        for (int m = 16; m >= 1; m >>= 1) ss += __shfl_xor(ss, m, 32);
        if (lane == 0) sRstd[tok] = rsqrtf(ss * (1.0f / DINv) + 1e-6f);
#pragma unroll
        for (int j = 0; j < 16; j++) sY[lane * 16 + j][tok] = v[j];
    }
    __syncthreads();

    // Phase G: GEMM 16 x 512 x 256
    const int c    = tid & 127;
    const int half = tid >> 7;       // 0..3, rows half*128..+127
    float A0[16], A1[16];
#pragma unroll
    for (int i = 0; i < 16; i++) { A0[i] = 0.f; A1[i] = 0.f; }
    const float* wb = Woutp + (size_t)(half * 128) * Hd;
    const float* gb = gnp + half * 128;
#pragma unroll 2
    for (int rr = 0; rr < 128; rr++) {
        const float g  = gb[rr];
        const float w0 = wb[rr * Hd + c] * g;
        const float w1 = wb[rr * Hd + c + 128] * g;
        const int r = half * 128 + rr;
        const float4* xp = (const float4*)&sY[r][0];
        float4 xq0 = xp[0], xq1 = xp[1], xq2 = xp[2], xq3 = xp[3];
        float xs[16] = {xq0.x,xq0.y,xq0.z,xq0.w, xq1.x,xq1.y,xq1.z,xq1.w,
                        xq2.x,xq2.y,xq2.z,xq2.w, xq3.x,xq3.y,xq3.z,xq3.w};
#pragma unroll
        for (int i = 0; i < 16; i++) {
            A0[i] = fmaf(xs[i], w0, A0[i]);
            A1[i] = fmaf(xs[i], w1, A1[i]);
        }
    }
    __syncthreads();   // all sY reads done; reuse as reduce buffer

    float (*red)[16] = (float(*)[16])sY;   // [256][16]
    if (half == 0) {
#pragma unroll
        for (int i = 0; i < 16; i++) { red[c][i] = A0[i]; red[c + 128][i] = A1[i]; }
    }
    __syncthreads();
    if (half == 1) {
#pragma unroll
        for (int i = 0; i < 16; i++) { red[c][i] += A0[i]; red[c + 128][i] += A1[i]; }
    }
    __syncthreads();
    if (half == 2) {
#pragma unroll
        for (int i = 0; i < 16; i++) { red[c][i] += A0[i]; red[c + 128][i] += A1[i]; }
    }
    __syncthreads();
    if (half == 3) {
#pragma unroll
        for (int i = 0; i < 16; i++) { red[c][i] += A0[i]; red[c + 128][i] += A1[i]; }
    }
    __syncthreads();

    // Epilogue: scale by rstd, add residual, store (transposed for time pass)
    {
        const int col = tid & 255;
        const int tb  = (tid >> 8) * 8;
#pragma unroll
        for (int j = 0; j < 8; j++) {
            const int tok = tb + j;
            const size_t inrow = (size_t)(R0 + tok);
            const float v = red[col][tok] * sRstd[tok] + src[inrow * Hd + col];
            size_t orow;
            if (TMODE) {
                const size_t sq = inrow >> 9;        // L = 512
                const size_t t  = inrow & 511;
                orow = ((sq >> 6) * 512 + t) * 64 + (sq & 63);
            } else {
                orow = inrow;
            }
            dst[orow * Hd + col] = v;
        }
    }
}

extern "C" void kernel_launch(void* const* d_in, const int* in_sizes, int n_in,
                              void* d_out, int out_size, void* d_ws, size_t ws_size,
                              hipStream_t stream) {
    const float* x      = (const float*)d_in[0];
    const float* t_norm = (const float*)d_in[1];
    const float* t_Win  = (const float*)d_in[2];
    const float* t_cw   = (const float*)d_in[3];
    const float* t_cb   = (const float*)d_in[4];
    const float* t_dtb  = (const float*)d_in[5];
    const float* t_Alog = (const float*)d_in[6];
    const float* t_D    = (const float*)d_in[7];
    const float* t_gn   = (const float*)d_in[8];
    const float* t_Wout = (const float*)d_in[9];
    const float* b_norm = (const float*)d_in[10];
    const float* b_Win  = (const float*)d_in[11];
    const float* b_cw   = (const float*)d_in[12];
    const float* b_cb   = (const float*)d_in[13];
    const float* b_dtb  = (const float*)d_in[14];
    const float* b_Alog = (const float*)d_in[15];
    const float* b_D    = (const float*)d_in[16];
    const float* b_gn   = (const float*)d_in[17];
    const float* b_Wout = (const float*)d_in[18];

    float* out  = (float*)d_out;
    float* xbuf = (float*)d_ws;                                            // 64 MB canonical ping
    unsigned short* zx = (unsigned short*)((char*)d_ws + (size_t)64 * 1024 * 1024); // 145 MB zxbcdt bf16

    const int NB = NTOK / 16;   // 4096 blocks for K1/K3

    for (int i = 0; i < NLAY; i++) {
        const float* src_t = (i == 0) ? x : out;
        // ---- time pass: 128 seqs of L=512, transposed store ----
        k1_proj<<<NB, 512, 0, stream>>>(src_t, zx, t_norm + i * Hd,
                                        t_Win + (size_t)i * Hd * PROJv);
        k2_scan<<<dim3(128, NHEADS), 64, 0, stream>>>(zx,
                 t_cw + i * 4 * CONVDv, t_cb + i * CONVDv, t_dtb + i * NHEADS,
                 t_Alog + i * NHEADS, t_D + i * NHEADS, 512);
        k3_out<true><<<NB, 512, 0, stream>>>(zx, src_t, xbuf,
                 t_Wout + (size_t)i * DINv * Hd, t_gn + i * DINv);
        // ---- band pass: 1024 seqs of L=64, identity store ----
        k1_proj<<<NB, 512, 0, stream>>>(xbuf, zx, b_norm + i * Hd,
                                        b_Win + (size_t)i * Hd * PROJv);
        k2_scan<<<dim3(1024, NHEADS), 64, 0, stream>>>(zx,
                 b_cw + i * 4 * CONVDv, b_cb + i * CONVDv, b_dtb + i * NHEADS,
                 b_Alog + i * NHEADS, b_D + i * NHEADS, 64);
        k3_out<false><<<NB, 512, 0, stream>>>(zx, xbuf, out,
                 b_Wout + (size_t)i * DINv * Hd, b_gn + i * DINv);
    }
}

// Round 4
// 18840.808 us; speedup vs baseline: 2.0306x; 1.0041x over previous
//
#include <hip/hip_runtime.h>
#include <math.h>

#define NLAY   6
#define Hd     256
#define DINv   512
#define NHEADS 8
#define CONVDv 640
#define PROJv  1160   // 2*DIN + 2*N + HEADS
#define PROJP  1168   // padded to 73 MFMA col-tiles
#define NTOK   65536

typedef __attribute__((ext_vector_type(8))) short bf16x8;
typedef __attribute__((ext_vector_type(4))) float f32x4;
typedef unsigned short u16;

__device__ __forceinline__ float siluf(float v) { return v / (1.0f + expf(-v)); }
__device__ __forceinline__ float bflo(unsigned u) { return __uint_as_float(u << 16); }
__device__ __forceinline__ float bfhi(unsigned u) { return __uint_as_float(u & 0xffff0000u); }
__device__ __forceinline__ u16 f2b(float f) {  // RNE fp32->bf16
    unsigned u = __float_as_uint(f);
    return (u16)((u + 0x7fffu + ((u >> 16) & 1u)) >> 16);
}
__device__ __forceinline__ float b2f(u16 s) { return __uint_as_float(((unsigned)s) << 16); }

// ---------- prep: Win (12 layers) -> bf16 hi/lo transposed [li][col(1168)][k(256)] ----------
__global__ __launch_bounds__(256)
void kprep_win(const float* __restrict__ tW, const float* __restrict__ bW,
               u16* __restrict__ Whi, u16* __restrict__ Wlo)
{
    const int li  = blockIdx.y;       // 0..11 (0..5 = time, 6..11 = band)
    const int col = blockIdx.x;       // 0..1167
    const int k   = threadIdx.x;      // 0..255
    const float* W = (li < 6) ? (tW + (size_t)li * Hd * PROJv)
                              : (bW + (size_t)(li - 6) * Hd * PROJv);
    float v = (col < PROJv) ? W[(size_t)k * PROJv + col] : 0.f;
    u16 hi = f2b(v);
    const size_t idx = ((size_t)li * PROJP + col) * Hd + k;
    Whi[idx] = hi;
    Wlo[idx] = f2b(v - b2f(hi));
}

// ---------- prep: Wout*gn -> bf16 hi/lo transposed [li][c(256)][r(512)] ----------
__global__ __launch_bounds__(512)
void kprep_wout(const float* __restrict__ tW, const float* __restrict__ tg,
                const float* __restrict__ bW, const float* __restrict__ bg,
                u16* __restrict__ Whi, u16* __restrict__ Wlo)
{
    const int li = blockIdx.y;
    const int c  = blockIdx.x;        // 0..255
    const int r  = threadIdx.x;       // 0..511
    const float* W = (li < 6) ? tW + (size_t)li * DINv * Hd : bW + (size_t)(li - 6) * DINv * Hd;
    const float* g = (li < 6) ? tg + li * DINv : bg + (li - 6) * DINv;
    float v = W[(size_t)r * Hd + c] * g[r];
    u16 hi = f2b(v);
    const size_t idx = ((size_t)li * Hd + c) * DINv + r;
    Whi[idx] = hi;
    Wlo[idx] = f2b(v - b2f(hi));
}

// ---------- K1: rmsnorm(x) @ Win -> zx bf16, MFMA with hi/lo split ----------
// grid (2048, 2): 32 tokens/block, col-group split. 8 waves.
__global__ __launch_bounds__(512, 2)
void k1_mfma(const float* __restrict__ src, u16* __restrict__ zx,
             const float* __restrict__ nw,
             const u16* __restrict__ Whi, const u16* __restrict__ Wlo)
{
    __shared__ __align__(16) u16 sAh[32 * 264];
    __shared__ __align__(16) u16 sAl[32 * 264];
    const int tid = threadIdx.x;
    const int R0  = blockIdx.x * 32;
    const int grp = blockIdx.y;               // 0: tiles 0..36, 1: tiles 37..72

    // load 32x256 fp32, rmsnorm, hi/lo bf16 -> LDS
    {
        const int tok = tid >> 4, l16 = tid & 15;
        const float* xr = src + ((size_t)(R0 + tok)) * Hd + l16 * 16;
        float4 v0 = ((const float4*)xr)[0];
        float4 v1 = ((const float4*)xr)[1];
        float4 v2 = ((const float4*)xr)[2];
        float4 v3 = ((const float4*)xr)[3];
        float vv[16] = {v0.x,v0.y,v0.z,v0.w, v1.x,v1.y,v1.z,v1.w,
                        v2.x,v2.y,v2.z,v2.w, v3.x,v3.y,v3.z,v3.w};
        float ss = 0.f;
#pragma unroll
        for (int j = 0; j < 16; j++) ss += vv[j] * vv[j];
#pragma unroll
        for (int m = 8; m >= 1; m >>= 1) ss += __shfl_xor(ss, m, 16);
        const float rstd = rsqrtf(ss * (1.0f / Hd) + 1e-6f);
        const float* nr = nw + l16 * 16;
        u16* dh = sAh + tok * 264 + l16 * 16;
        u16* dl = sAl + tok * 264 + l16 * 16;
#pragma unroll
        for (int j = 0; j < 16; j++) {
            const float val = vv[j] * rstd * nr[j];
            const u16 hi = f2b(val);
            dh[j] = hi;
            dl[j] = f2b(val - b2f(hi));
        }
    }
    __syncthreads();

    const int lane = tid & 63, wave = tid >> 6;
    const int rh = wave & 1, cq = wave >> 1;
    const int quad = lane >> 4, m16 = lane & 15;

    bf16x8 ah[8], al[8];
    {
        const u16* ph = sAh + (rh * 16 + m16) * 264 + quad * 8;
        const u16* pl = sAl + (rh * 16 + m16) * 264 + quad * 8;
#pragma unroll
        for (int kk = 0; kk < 8; kk++) {
            ah[kk] = *(const bf16x8*)(ph + kk * 32);
            al[kk] = *(const bf16x8*)(pl + kk * 32);
        }
    }

    const int jlim = grp ? 36 : 37;           // tiles in this group
    f32x4 acc[10];
#pragma unroll
    for (int t = 0; t < 10; t++) acc[t] = (f32x4){0.f, 0.f, 0.f, 0.f};

#pragma unroll
    for (int jj = 0; jj < 10; jj++) {
        const int jl = cq + 4 * jj;
        const int j  = grp * 37 + ((jl < jlim) ? jl : cq);   // clamp to a valid tile
        const size_t boff = ((size_t)(16 * j + m16)) * Hd + quad * 8;
        const u16* bh = Whi + boff;
        const u16* bl = Wlo + boff;
#pragma unroll
        for (int kk = 0; kk < 8; kk++) {
            bf16x8 bhv = *(const bf16x8*)(bh + kk * 32);
            bf16x8 blv = *(const bf16x8*)(bl + kk * 32);
            acc[jj] = __builtin_amdgcn_mfma_f32_16x16x32_bf16(ah[kk], bhv, acc[jj], 0, 0, 0);
            acc[jj] = __builtin_amdgcn_mfma_f32_16x16x32_bf16(al[kk], bhv, acc[jj], 0, 0, 0);
            acc[jj] = __builtin_amdgcn_mfma_f32_16x16x32_bf16(ah[kk], blv, acc[jj], 0, 0, 0);
        }
    }

    // store D (col=lane&15, row=quad*4+i) as bf16
    u16* zr = zx + (size_t)(R0 + rh * 16 + quad * 4) * PROJP + m16;
#pragma unroll
    for (int jj = 0; jj < 10; jj++) {
        const int jl = cq + 4 * jj;
        if (jl >= jlim) continue;             // wave-uniform
        const int col0 = 16 * (grp * 37 + jl);
#pragma unroll
        for (int i = 0; i < 4; i++)
            zr[(size_t)i * PROJP + col0] = f2b(acc[jj][i]);
    }
}

// ---------- K2: conv4+silu, softplus/dA, scan, silu(z) gate (in place over z cols) ----------
__global__ __launch_bounds__(64, 3)
void k2_scan(u16* __restrict__ zx,
             const float* __restrict__ cwp, const float* __restrict__ cbp,
             const float* __restrict__ dtbp, const float* __restrict__ alogp,
             const float* __restrict__ Dp, int L)
{
    __shared__ __align__(16) float sB[64];
    __shared__ __align__(16) float sC[64];
    const int p    = threadIdx.x;
    const int head = blockIdx.y;
    const int s    = blockIdx.x;
    const int chx  = head * 64 + p;

    float cx0 = cwp[0*CONVDv + chx], cx1 = cwp[1*CONVDv + chx],
          cx2 = cwp[2*CONVDv + chx], cx3 = cwp[3*CONVDv + chx];
    float cb0_ = cbp[chx];
    float bb0 = cwp[0*CONVDv + 512 + p], bb1 = cwp[1*CONVDv + 512 + p],
          bb2 = cwp[2*CONVDv + 512 + p], bb3 = cwp[3*CONVDv + 512 + p];
    float cbb = cbp[512 + p];
    float cc0 = cwp[0*CONVDv + 576 + p], cc1 = cwp[1*CONVDv + 576 + p],
          cc2 = cwp[2*CONVDv + 576 + p], cc3 = cwp[3*CONVDv + 576 + p];
    float cbc = cbp[576 + p];

    const float dtb = dtbp[head];
    const float nA  = -expf(alogp[head]);
    const float Dh  = Dp[head];

    float wx0 = 0.f, wx1 = 0.f, wx2 = 0.f;
    float wb0 = 0.f, wb1 = 0.f, wb2 = 0.f;
    float wc0 = 0.f, wc1 = 0.f, wc2 = 0.f;

    float h[64];
#pragma unroll
    for (int n = 0; n < 64; n++) h[n] = 0.f;

    const size_t base = (size_t)s * L * PROJP;
    const u16* rp = zx + base;
    u16 nx = rp[512 + chx], nb = rp[1024 + p], nc = rp[1088 + p],
        ndt = rp[1152 + head], nz = rp[chx];

    for (int t = 0; t < L; t++) {
        const u16 rcx = nx, rcb = nb, rcc = nc, rcd = ndt, rcz = nz;
        if (t + 1 < L) {   // raw prefetch; conversion deferred so vmcnt wait sinks
            const u16* rn = zx + base + (size_t)(t + 1) * PROJP;
            nx  = rn[512 + chx];
            nb  = rn[1024 + p];
            nc  = rn[1088 + p];
            ndt = rn[1152 + head];
            nz  = rn[chx];
        }
        const float dts = b2f(rcd) + dtb;
        const float sp  = (dts > 20.f) ? dts : log1pf(expf(dts));
        const float dA  = expf(nA * sp);

        const float xr = b2f(rcx), br = b2f(rcb), cr = b2f(rcc);
        float xv = siluf(cb0_ + cx0*wx0 + cx1*wx1 + cx2*wx2 + cx3*xr);
        wx0 = wx1; wx1 = wx2; wx2 = xr;
        float bv = siluf(cbb + bb0*wb0 + bb1*wb1 + bb2*wb2 + bb3*br);
        wb0 = wb1; wb1 = wb2; wb2 = br;
        float cv = siluf(cbc + cc0*wc0 + cc1*wc1 + cc2*wc2 + cc3*cr);
        wc0 = wc1; wc1 = wc2; wc2 = cr;

        sB[p] = bv;
        sC[p] = cv;
        const float xdt = xv * sp;
        float y0 = 0.f, y1 = 0.f, y2 = 0.f, y3 = 0.f;
        const float4* B4 = (const float4*)sB;
        const float4* C4 = (const float4*)sC;
#pragma unroll
        for (int q = 0; q < 16; q++) {
            float4 bq = B4[q], cq = C4[q];
            h[4*q+0] = fmaf(dA, h[4*q+0], xdt * bq.x); y0 = fmaf(h[4*q+0], cq.x, y0);
            h[4*q+1] = fmaf(dA, h[4*q+1], xdt * bq.y); y1 = fmaf(h[4*q+1], cq.y, y1);
            h[4*q+2] = fmaf(dA, h[4*q+2], xdt * bq.z); y2 = fmaf(h[4*q+2], cq.z, y2);
            h[4*q+3] = fmaf(dA, h[4*q+3], xdt * bq.w); y3 = fmaf(h[4*q+3], cq.w, y3);
        }
        const float y = fmaf(Dh, xv, (y0 + y1) + (y2 + y3));
        zx[base + (size_t)t * PROJP + chx] = f2b(y * siluf(b2f(rcz)));
    }
}

// ---------- K3: rmsnorm(gated y) @ (gn*Wout) + residual -> dst, MFMA hi/lo ----------
template<bool TMODE>
__global__ __launch_bounds__(512, 2)
void k3_mfma(const u16* __restrict__ zx, const float* __restrict__ src,
             float* __restrict__ dst,
             const u16* __restrict__ Whi, const u16* __restrict__ Wlo)
{
    __shared__ __align__(16) u16 sAh[32 * 520];
    __shared__ __align__(16) u16 sAl[32 * 520];
    const int tid = threadIdx.x;
    const int R0  = blockIdx.x * 32;

    // load 32x512 bf16 gated-y, rmsnorm, hi/lo bf16 -> LDS
    {
        const int tok = tid >> 4, l16 = tid & 15;
        const u16* yr = zx + (size_t)(R0 + tok) * PROJP + l16 * 32;
        const uint4* yp = (const uint4*)yr;
        uint4 u0 = yp[0], u1 = yp[1], u2 = yp[2], u3 = yp[3];
        unsigned uu[16] = {u0.x,u0.y,u0.z,u0.w, u1.x,u1.y,u1.z,u1.w,
                           u2.x,u2.y,u2.z,u2.w, u3.x,u3.y,u3.z,u3.w};
        float v[32];
#pragma unroll
        for (int k = 0; k < 16; k++) { v[2*k] = bflo(uu[k]); v[2*k+1] = bfhi(uu[k]); }
        float ss = 0.f;
#pragma unroll
        for (int j = 0; j < 32; j++) ss += v[j] * v[j];
#pragma unroll
        for (int m = 8; m >= 1; m >>= 1) ss += __shfl_xor(ss, m, 16);
        const float rstd = rsqrtf(ss * (1.0f / DINv) + 1e-6f);
        u16* dh = sAh + tok * 520 + l16 * 32;
        u16* dl = sAl + tok * 520 + l16 * 32;
#pragma unroll
        for (int j = 0; j < 32; j++) {
            const float val = v[j] * rstd;
            const u16 hi = f2b(val);
            dh[j] = hi;
            dl[j] = f2b(val - b2f(hi));
        }
    }
    __syncthreads();

    const int lane = tid & 63, wave = tid >> 6;
    const int rh = wave & 1, cq = wave >> 1;
    const int quad = lane >> 4, m16 = lane & 15;

    f32x4 acc[4];
#pragma unroll
    for (int t = 0; t < 4; t++) acc[t] = (f32x4){0.f, 0.f, 0.f, 0.f};

    const u16* aph = sAh + (rh * 16 + m16) * 520 + quad * 8;
    const u16* apl = sAl + (rh * 16 + m16) * 520 + quad * 8;
#pragma unroll
    for (int kk = 0; kk < 16; kk++) {
        bf16x8 a_h = *(const bf16x8*)(aph + kk * 32);
        bf16x8 a_l = *(const bf16x8*)(apl + kk * 32);
#pragma unroll
        for (int t = 0; t < 4; t++) {
            const int j = cq + 4 * t;
            const size_t boff = ((size_t)(16 * j + m16)) * DINv + kk * 32 + quad * 8;
            bf16x8 b_h = *(const bf16x8*)(Whi + boff);
            bf16x8 b_l = *(const bf16x8*)(Wlo + boff);
            acc[t] = __builtin_amdgcn_mfma_f32_16x16x32_bf16(a_h, b_h, acc[t], 0, 0, 0);
            acc[t] = __builtin_amdgcn_mfma_f32_16x16x32_bf16(a_l, b_h, acc[t], 0, 0, 0);
            acc[t] = __builtin_amdgcn_mfma_f32_16x16x32_bf16(a_h, b_l, acc[t], 0, 0, 0);
        }
    }

    // epilogue: + residual, store fp32 (transposed rows for time pass)
#pragma unroll
    for (int t = 0; t < 4; t++) {
        const int col = 16 * (cq + 4 * t) + m16;
#pragma unroll
        for (int i = 0; i < 4; i++) {
            const size_t inrow = (size_t)(R0 + rh * 16 + quad * 4 + i);
            const float v = acc[t][i] + src[inrow * Hd + col];
            size_t orow;
            if (TMODE) {
                const size_t sq = inrow >> 9;
                const size_t tt = inrow & 511;
                orow = ((sq >> 6) * 512 + tt) * 64 + (sq & 63);
            } else {
                orow = inrow;
            }
            dst[orow * Hd + col] = v;
        }
    }
}

extern "C" void kernel_launch(void* const* d_in, const int* in_sizes, int n_in,
                              void* d_out, int out_size, void* d_ws, size_t ws_size,
                              hipStream_t stream) {
    const float* x      = (const float*)d_in[0];
    const float* t_norm = (const float*)d_in[1];
    const float* t_Win  = (const float*)d_in[2];
    const float* t_cw   = (const float*)d_in[3];
    const float* t_cb   = (const float*)d_in[4];
    const float* t_dtb  = (const float*)d_in[5];
    const float* t_Alog = (const float*)d_in[6];
    const float* t_D    = (const float*)d_in[7];
    const float* t_gn   = (const float*)d_in[8];
    const float* t_Wout = (const float*)d_in[9];
    const float* b_norm = (const float*)d_in[10];
    const float* b_Win  = (const float*)d_in[11];
    const float* b_cw   = (const float*)d_in[12];
    const float* b_cb   = (const float*)d_in[13];
    const float* b_dtb  = (const float*)d_in[14];
    const float* b_Alog = (const float*)d_in[15];
    const float* b_D    = (const float*)d_in[16];
    const float* b_gn   = (const float*)d_in[17];
    const float* b_Wout = (const float*)d_in[18];

    float* out = (float*)d_out;
    char*  wsb = (char*)d_ws;
    // workspace layout (bytes):
    // xbuf 64MB | W1hi 7.18MB | W1lo 7.18MB | W2hi 3.15MB | W2lo 3.15MB | zx 153MB  (~238MB)
    float* xbuf = (float*)wsb;
    size_t off = 67108864;
    u16* W1hi = (u16*)(wsb + off); off += (size_t)12 * PROJP * Hd * 2;
    u16* W1lo = (u16*)(wsb + off); off += (size_t)12 * PROJP * Hd * 2;
    u16* W2hi = (u16*)(wsb + off); off += (size_t)12 * Hd * DINv * 2;
    u16* W2lo = (u16*)(wsb + off); off += (size_t)12 * Hd * DINv * 2;
    u16* zxb  = (u16*)(wsb + off);

    kprep_win<<<dim3(PROJP, 12), 256, 0, stream>>>(t_Win, b_Win, W1hi, W1lo);
    kprep_wout<<<dim3(Hd, 12), 512, 0, stream>>>(t_Wout, t_gn, b_Wout, b_gn, W2hi, W2lo);

    const int NB = NTOK / 32;   // 2048 token-blocks

    for (int i = 0; i < NLAY; i++) {
        const float* src_t = (i == 0) ? x : out;
        // ---- time pass: 128 seqs x L=512, transposed store ----
        k1_mfma<<<dim3(NB, 2), 512, 0, stream>>>(src_t, zxb, t_norm + i * Hd,
                 W1hi + (size_t)i * PROJP * Hd, W1lo + (size_t)i * PROJP * Hd);
        k2_scan<<<dim3(128, NHEADS), 64, 0, stream>>>(zxb,
                 t_cw + i * 4 * CONVDv, t_cb + i * CONVDv, t_dtb + i * NHEADS,
                 t_Alog + i * NHEADS, t_D + i * NHEADS, 512);
        k3_mfma<true><<<NB, 512, 0, stream>>>(zxb, src_t, xbuf,
                 W2hi + (size_t)i * Hd * DINv, W2lo + (size_t)i * Hd * DINv);
        // ---- band pass: 1024 seqs x L=64, identity store ----
        k1_mfma<<<dim3(NB, 2), 512, 0, stream>>>(xbuf, zxb, b_norm + i * Hd,
                 W1hi + (size_t)(i + 6) * PROJP * Hd, W1lo + (size_t)(i + 6) * PROJP * Hd);
        k2_scan<<<dim3(1024, NHEADS), 64, 0, stream>>>(zxb,
                 b_cw + i * 4 * CONVDv, b_cb + i * CONVDv, b_dtb + i * NHEADS,
                 b_Alog + i * NHEADS, b_D + i * NHEADS, 64);
        k3_mfma<false><<<NB, 512, 0, stream>>>(zxb, xbuf, out,
                 W2hi + (size_t)(i + 6) * Hd * DINv, W2lo + (size_t)(i + 6) * Hd * DINv);
    }
}

// Round 5
// 12651.180 us; speedup vs baseline: 3.0241x; 1.4893x over previous
//
#include <hip/hip_runtime.h>
#include <math.h>

#define NLAY   6
#define Hd     256
#define DINv   512
#define NHEADS 8
#define CONVDv 640
#define PROJv  1160   // 2*DIN + 2*N + HEADS
#define PROJP  1184   // padded to 74 MFMA col-tiles
#define NTOK   65536

typedef __attribute__((ext_vector_type(8))) short bf16x8;
typedef __attribute__((ext_vector_type(4))) float f32x4;
typedef unsigned short u16;

__device__ __forceinline__ float siluf(float v) { return v / (1.0f + expf(-v)); }
__device__ __forceinline__ float bflo(unsigned u) { return __uint_as_float(u << 16); }
__device__ __forceinline__ float bfhi(unsigned u) { return __uint_as_float(u & 0xffff0000u); }
__device__ __forceinline__ u16 f2b(float f) {  // RNE fp32->bf16
    unsigned u = __float_as_uint(f);
    return (u16)((u + 0x7fffu + ((u >> 16) & 1u)) >> 16);
}
__device__ __forceinline__ float b2f(u16 s) { return __uint_as_float(((unsigned)s) << 16); }

__device__ __forceinline__ void gl_lds16(const void* g, void* l) {
    __builtin_amdgcn_global_load_lds((const __attribute__((address_space(1))) unsigned int*)g,
                                     (__attribute__((address_space(3))) unsigned int*)l, 16, 0, 0);
}

// ---------- prep: Win -> bf16 hi/lo in MFMA-fragment order ----------
// layout: [li(12)][tile j(74)][kk(8)][col(16)][quad(4)][e(8)]  (tile = 4096 u16 = 8KB)
// element = W[k = kk*32+quad*8+e][fullcol = 16j+col]
__global__ __launch_bounds__(512)
void kprep_win(const float* __restrict__ tW, const float* __restrict__ bW,
               u16* __restrict__ Whi, u16* __restrict__ Wlo)
{
    const int li = blockIdx.y, j = blockIdx.x;    // j 0..73
    const int t  = threadIdx.x;
    const int kk = t >> 6, col = (t >> 2) & 15, quad = t & 3;
    const float* W = (li < 6) ? (tW + (size_t)li * Hd * PROJv)
                              : (bW + (size_t)(li - 6) * Hd * PROJv);
    const int fullcol = 16 * j + col;
    const size_t ob = ((size_t)li * 74 + j) * 4096 + kk * 512 + col * 32 + quad * 8;
#pragma unroll
    for (int e = 0; e < 8; e++) {
        const int k = kk * 32 + quad * 8 + e;
        const float v = (fullcol < PROJv) ? W[(size_t)k * PROJv + fullcol] : 0.f;
        const u16 hi = f2b(v);
        Whi[ob + e] = hi;
        Wlo[ob + e] = f2b(v - b2f(hi));
    }
}

// ---------- prep: Wout*gn -> bf16 hi/lo in MFMA-fragment order ----------
// layout: [li(12)][tile j(16)][kk(16)][col(16)][quad(4)][e(8)]  (tile = 8192 u16 = 16KB)
// element = (Wout[k][fullcol] * gn[k]), k = kk*32+quad*8+e (0..511)
__global__ __launch_bounds__(512)
void kprep_wout(const float* __restrict__ tW, const float* __restrict__ tg,
                const float* __restrict__ bW, const float* __restrict__ bg,
                u16* __restrict__ Whi, u16* __restrict__ Wlo)
{
    const int li = blockIdx.y, j = blockIdx.x;    // j 0..15
    const int t  = threadIdx.x;
    const int kk = t >> 5, col = (t >> 1) & 15, qh = t & 1;
    const float* W = (li < 6) ? tW + (size_t)li * DINv * Hd : bW + (size_t)(li - 6) * DINv * Hd;
    const float* g = (li < 6) ? tg + li * DINv : bg + (li - 6) * DINv;
    const int fullcol = 16 * j + col;
#pragma unroll
    for (int q = 0; q < 2; q++) {
        const int quad = qh * 2 + q;
        const size_t ob = ((size_t)li * 16 + j) * 8192 + kk * 512 + col * 32 + quad * 8;
#pragma unroll
        for (int e = 0; e < 8; e++) {
            const int k = kk * 32 + quad * 8 + e;
            const float v = W[(size_t)k * Hd + fullcol] * g[k];
            const u16 hi = f2b(v);
            Whi[ob + e] = hi;
            Wlo[ob + e] = f2b(v - b2f(hi));
        }
    }
}

// ---------- K1: rmsnorm(x) @ Win -> zx bf16. 64 tok/block, LDS-staged weights ----------
__global__ __launch_bounds__(512, 2)
void k1_mfma(const float* __restrict__ src, u16* __restrict__ zx,
             const float* __restrict__ nw,
             const u16* __restrict__ Whi, const u16* __restrict__ Wlo)
{
    __shared__ __align__(16) u16 sAh[64 * 264];
    __shared__ __align__(16) u16 sAl[64 * 264];
    __shared__ __align__(16) u16 sW[2][16384];    // dbuf x 32KB (pair: [t2][hi/lo] 8KB chunks)
    const int tid = threadIdx.x;
    const int R0  = blockIdx.x * 64;

    { // phase A: load 64x256 fp32, rmsnorm, hi/lo -> LDS
        const int tok = tid >> 3, l8 = tid & 7;
        const float* xr = src + ((size_t)(R0 + tok)) * Hd + l8 * 32;
        float vv[32];
#pragma unroll
        for (int q = 0; q < 8; q++) {
            float4 v = ((const float4*)xr)[q];
            vv[4*q] = v.x; vv[4*q+1] = v.y; vv[4*q+2] = v.z; vv[4*q+3] = v.w;
        }
        float ss = 0.f;
#pragma unroll
        for (int j = 0; j < 32; j++) ss += vv[j] * vv[j];
#pragma unroll
        for (int m = 4; m >= 1; m >>= 1) ss += __shfl_xor(ss, m, 8);
        const float rstd = rsqrtf(ss * (1.0f / Hd) + 1e-6f);
        const float* nr = nw + l8 * 32;
        u16* dh = sAh + tok * 264 + l8 * 32;
        u16* dl = sAl + tok * 264 + l8 * 32;
#pragma unroll
        for (int j = 0; j < 32; j++) {
            const float val = vv[j] * rstd * nr[j];
            const u16 hi = f2b(val);
            dh[j] = hi;
            dl[j] = f2b(val - b2f(hi));
        }
    }
    __syncthreads();

    const int lane = tid & 63, wave = tid >> 6;
    const int rh = wave >> 1, cw = wave & 1;      // 4 row-tiles x 2 col-slots
    const int quad = lane >> 4, m16 = lane & 15;

    bf16x8 ah[8], al[8];
    {
        const u16* ph = sAh + (rh * 16 + m16) * 264 + quad * 8;
        const u16* pl = sAl + (rh * 16 + m16) * 264 + quad * 8;
#pragma unroll
        for (int kk = 0; kk < 8; kk++) {
            ah[kk] = *(const bf16x8*)(ph + kk * 32);
            al[kk] = *(const bf16x8*)(pl + kk * 32);
        }
    }

    // stage pair p into buf: 32KB, each wave 4x1KB chunks
#define K1_STAGE(p, buf)                                                          \
    {                                                                             \
        const int obase = wave * 4096;                                            \
        _Pragma("unroll")                                                         \
        for (int i = 0; i < 4; i++) {                                             \
            const int o = obase + i * 1024;                                       \
            const int chunk = o >> 13, t2 = chunk >> 1, hl = chunk & 1;           \
            const int within = o & 8191;                                          \
            const u16* sbase = (hl ? Wlo : Whi) + (size_t)(2 * (p) + t2) * 4096;  \
            gl_lds16((const char*)sbase + within + lane * 16,                     \
                     (char*)&sW[buf][0] + o);                                     \
        }                                                                         \
    }

    K1_STAGE(0, 0);
    __syncthreads();

    for (int p = 0; p < 37; p++) {
        if (p < 36) K1_STAGE(p + 1, (p + 1) & 1);
        const int j = 2 * p + cw;
        const u16* tb = &sW[p & 1][cw * 8192] + m16 * 32 + quad * 8;
        f32x4 acc = (f32x4){0.f, 0.f, 0.f, 0.f};
#pragma unroll
        for (int kk = 0; kk < 8; kk++) {
            bf16x8 bh = *(const bf16x8*)(tb + kk * 512);
            bf16x8 bl = *(const bf16x8*)(tb + 4096 + kk * 512);
            acc = __builtin_amdgcn_mfma_f32_16x16x32_bf16(ah[kk], bh, acc, 0, 0, 0);
            acc = __builtin_amdgcn_mfma_f32_16x16x32_bf16(al[kk], bh, acc, 0, 0, 0);
            acc = __builtin_amdgcn_mfma_f32_16x16x32_bf16(ah[kk], bl, acc, 0, 0, 0);
        }
        u16* zr = zx + (size_t)(R0 + rh * 16 + quad * 4) * PROJP + 16 * j + m16;
#pragma unroll
        for (int i = 0; i < 4; i++) zr[(size_t)i * PROJP] = f2b(acc[i]);
        __syncthreads();
    }
#undef K1_STAGE
}

// ---------- K2: conv4+silu, softplus/dA, scan, silu(z) gate; prefetch depth 4 ----------
__global__ __launch_bounds__(64, 3)
void k2_scan(u16* __restrict__ zx,
             const float* __restrict__ cwp, const float* __restrict__ cbp,
             const float* __restrict__ dtbp, const float* __restrict__ alogp,
             const float* __restrict__ Dp, int L)
{
    __shared__ __align__(16) float sB[64];
    __shared__ __align__(16) float sC[64];
    const int p    = threadIdx.x;
    const int head = blockIdx.y;
    const int s    = blockIdx.x;
    const int chx  = head * 64 + p;

    float cx0 = cwp[0*CONVDv + chx], cx1 = cwp[1*CONVDv + chx],
          cx2 = cwp[2*CONVDv + chx], cx3 = cwp[3*CONVDv + chx];
    float cb0_ = cbp[chx];
    float bb0 = cwp[0*CONVDv + 512 + p], bb1 = cwp[1*CONVDv + 512 + p],
          bb2 = cwp[2*CONVDv + 512 + p], bb3 = cwp[3*CONVDv + 512 + p];
    float cbb = cbp[512 + p];
    float cc0 = cwp[0*CONVDv + 576 + p], cc1 = cwp[1*CONVDv + 576 + p],
          cc2 = cwp[2*CONVDv + 576 + p], cc3 = cwp[3*CONVDv + 576 + p];
    float cbc = cbp[576 + p];

    const float dtb = dtbp[head];
    const float nA  = -expf(alogp[head]);
    const float Dh  = Dp[head];

    float wx0 = 0.f, wx1 = 0.f, wx2 = 0.f;
    float wb0 = 0.f, wb1 = 0.f, wb2 = 0.f;
    float wc0 = 0.f, wc1 = 0.f, wc2 = 0.f;

    float h[64];
#pragma unroll
    for (int n = 0; n < 64; n++) h[n] = 0.f;

    const size_t base = (size_t)s * L * PROJP;
    u16 fx[4], fb[4], fc[4], fd[4], fz[4];
#pragma unroll
    for (int i = 0; i < 4; i++) {          // L >= 64 always
        const u16* r = zx + base + (size_t)i * PROJP;
        fx[i] = r[512 + chx]; fb[i] = r[1024 + p]; fc[i] = r[1088 + p];
        fd[i] = r[1152 + head]; fz[i] = r[chx];
    }

#pragma unroll 4
    for (int t = 0; t < L; t++) {
        const int sl = t & 3;
        const u16 rcx = fx[sl], rcb = fb[sl], rcc = fc[sl], rcd = fd[sl], rcz = fz[sl];
        if (t + 4 < L) {                   // refill slot, 4 tokens ahead
            const u16* rn = zx + base + (size_t)(t + 4) * PROJP;
            fx[sl] = rn[512 + chx]; fb[sl] = rn[1024 + p]; fc[sl] = rn[1088 + p];
            fd[sl] = rn[1152 + head]; fz[sl] = rn[chx];
        }
        const float dts = b2f(rcd) + dtb;
        const float sp  = (dts > 20.f) ? dts : log1pf(expf(dts));
        const float dA  = expf(nA * sp);

        const float xr = b2f(rcx), br = b2f(rcb), cr = b2f(rcc);
        float xv = siluf(cb0_ + cx0*wx0 + cx1*wx1 + cx2*wx2 + cx3*xr);
        wx0 = wx1; wx1 = wx2; wx2 = xr;
        float bv = siluf(cbb + bb0*wb0 + bb1*wb1 + bb2*wb2 + bb3*br);
        wb0 = wb1; wb1 = wb2; wb2 = br;
        float cv = siluf(cbc + cc0*wc0 + cc1*wc1 + cc2*wc2 + cc3*cr);
        wc0 = wc1; wc1 = wc2; wc2 = cr;

        sB[p] = bv;
        sC[p] = cv;
        const float xdt = xv * sp;
        float y0 = 0.f, y1 = 0.f, y2 = 0.f, y3 = 0.f;
        const float4* B4 = (const float4*)sB;
        const float4* C4 = (const float4*)sC;
#pragma unroll
        for (int q = 0; q < 16; q++) {
            float4 bq = B4[q], cq = C4[q];
            h[4*q+0] = fmaf(dA, h[4*q+0], xdt * bq.x); y0 = fmaf(h[4*q+0], cq.x, y0);
            h[4*q+1] = fmaf(dA, h[4*q+1], xdt * bq.y); y1 = fmaf(h[4*q+1], cq.y, y1);
            h[4*q+2] = fmaf(dA, h[4*q+2], xdt * bq.z); y2 = fmaf(h[4*q+2], cq.z, y2);
            h[4*q+3] = fmaf(dA, h[4*q+3], xdt * bq.w); y3 = fmaf(h[4*q+3], cq.w, y3);
        }
        const float y = fmaf(Dh, xv, (y0 + y1) + (y2 + y3));
        zx[base + (size_t)t * PROJP + chx] = f2b(y * siluf(b2f(rcz)));
    }
}

// ---------- K3: rmsnorm(gated y) @ (gn*Wout) + residual -> dst. 64 tok/block ----------
template<bool TMODE>
__global__ __launch_bounds__(512, 2)
void k3_mfma(const u16* __restrict__ zx, const float* __restrict__ src,
             float* __restrict__ dst,
             const u16* __restrict__ Whi, const u16* __restrict__ Wlo)
{
    __shared__ __align__(16) char smem[133120];   // sA (133120B) overlaid later by sW (131072B)
    u16* sAh = (u16*)smem;                        // 64*520
    u16* sAl = sAh + 64 * 520;
    u16* sW  = (u16*)smem;                        // 2 bufs x 32768 u16 (pair: [t2][hi/lo] 16KB chunks)
    const int tid = threadIdx.x;
    const int R0  = blockIdx.x * 64;

    { // phase A: load 64x512 bf16 gated-y, rmsnorm, hi/lo -> LDS
        const int tok = tid >> 3, l8 = tid & 7;
        const u16* yr = zx + (size_t)(R0 + tok) * PROJP + l8 * 64;
        float v[64];
#pragma unroll
        for (int q = 0; q < 8; q++) {
            uint4 u = ((const uint4*)yr)[q];
            unsigned uu[4] = {u.x, u.y, u.z, u.w};
#pragma unroll
            for (int w2 = 0; w2 < 4; w2++) {
                v[8*q + 2*w2]     = bflo(uu[w2]);
                v[8*q + 2*w2 + 1] = bfhi(uu[w2]);
            }
        }
        float ss = 0.f;
#pragma unroll
        for (int j = 0; j < 64; j++) ss += v[j] * v[j];
#pragma unroll
        for (int m = 4; m >= 1; m >>= 1) ss += __shfl_xor(ss, m, 8);
        const float rstd = rsqrtf(ss * (1.0f / DINv) + 1e-6f);
        u16* dh = sAh + tok * 520 + l8 * 64;
        u16* dl = sAl + tok * 520 + l8 * 64;
#pragma unroll
        for (int j = 0; j < 64; j++) {
            const float val = v[j] * rstd;
            const u16 hi = f2b(val);
            dh[j] = hi;
            dl[j] = f2b(val - b2f(hi));
        }
    }
    __syncthreads();

    const int lane = tid & 63, wave = tid >> 6;
    const int rh = wave >> 1, cw = wave & 1;
    const int quad = lane >> 4, m16 = lane & 15;

    bf16x8 ah[16], al[16];
    {
        const u16* ph = sAh + (rh * 16 + m16) * 520 + quad * 8;
        const u16* pl = sAl + (rh * 16 + m16) * 520 + quad * 8;
#pragma unroll
        for (int kk = 0; kk < 16; kk++) {
            ah[kk] = *(const bf16x8*)(ph + kk * 32);
            al[kk] = *(const bf16x8*)(pl + kk * 32);
        }
    }
    __syncthreads();   // all sA reads complete before sW overlay is written

    // stage pair p into buf: 64KB, each wave 8x1KB chunks
#define K3_STAGE(p, buf)                                                          \
    {                                                                             \
        const int obase = wave * 8192;                                            \
        _Pragma("unroll")                                                         \
        for (int i = 0; i < 8; i++) {                                             \
            const int o = obase + i * 1024;                                       \
            const int chunk = o >> 14, t2 = chunk >> 1, hl = chunk & 1;           \
            const int within = o & 16383;                                         \
            const u16* sbase = (hl ? Wlo : Whi) + (size_t)(2 * (p) + t2) * 8192;  \
            gl_lds16((const char*)sbase + within + lane * 16,                     \
                     (char*)sW + (buf) * 65536 + o);                              \
        }                                                                         \
    }

    K3_STAGE(0, 0);
    __syncthreads();

    for (int p = 0; p < 8; p++) {
        if (p < 7) K3_STAGE(p + 1, (p + 1) & 1);
        const int j = 2 * p + cw;
        const u16* tb = sW + (p & 1) * 32768 + cw * 16384 + m16 * 32 + quad * 8;
        f32x4 acc = (f32x4){0.f, 0.f, 0.f, 0.f};
#pragma unroll
        for (int kk = 0; kk < 16; kk++) {
            bf16x8 bh = *(const bf16x8*)(tb + kk * 512);
            bf16x8 bl = *(const bf16x8*)(tb + 8192 + kk * 512);
            acc = __builtin_amdgcn_mfma_f32_16x16x32_bf16(ah[kk], bh, acc, 0, 0, 0);
            acc = __builtin_amdgcn_mfma_f32_16x16x32_bf16(al[kk], bh, acc, 0, 0, 0);
            acc = __builtin_amdgcn_mfma_f32_16x16x32_bf16(ah[kk], bl, acc, 0, 0, 0);
        }
        const int col = 16 * j + m16;
#pragma unroll
        for (int i = 0; i < 4; i++) {
            const size_t inrow = (size_t)(R0 + rh * 16 + quad * 4 + i);
            const float v = acc[i] + src[inrow * Hd + col];
            size_t orow;
            if (TMODE) {
                const size_t sq = inrow >> 9;
                const size_t tt = inrow & 511;
                orow = ((sq >> 6) * 512 + tt) * 64 + (sq & 63);
            } else {
                orow = inrow;
            }
            dst[orow * Hd + col] = v;
        }
        __syncthreads();
    }
#undef K3_STAGE
}

extern "C" void kernel_launch(void* const* d_in, const int* in_sizes, int n_in,
                              void* d_out, int out_size, void* d_ws, size_t ws_size,
                              hipStream_t stream) {
    const float* x      = (const float*)d_in[0];
    const float* t_norm = (const float*)d_in[1];
    const float* t_Win  = (const float*)d_in[2];
    const float* t_cw   = (const float*)d_in[3];
    const float* t_cb   = (const float*)d_in[4];
    const float* t_dtb  = (const float*)d_in[5];
    const float* t_Alog = (const float*)d_in[6];
    const float* t_D    = (const float*)d_in[7];
    const float* t_gn   = (const float*)d_in[8];
    const float* t_Wout = (const float*)d_in[9];
    const float* b_norm = (const float*)d_in[10];
    const float* b_Win  = (const float*)d_in[11];
    const float* b_cw   = (const float*)d_in[12];
    const float* b_cb   = (const float*)d_in[13];
    const float* b_dtb  = (const float*)d_in[14];
    const float* b_Alog = (const float*)d_in[15];
    const float* b_D    = (const float*)d_in[16];
    const float* b_gn   = (const float*)d_in[17];
    const float* b_Wout = (const float*)d_in[18];

    float* out = (float*)d_out;
    char*  wsb = (char*)d_ws;
    // ws layout: xbuf 64MB | W1hi 7.27MB | W1lo | W2hi 3.15MB | W2lo | zx 155MB  (~232MB)
    float* xbuf = (float*)wsb;
    size_t off = 67108864;
    u16* W1hi = (u16*)(wsb + off); off += (size_t)12 * 74 * 4096 * 2;
    u16* W1lo = (u16*)(wsb + off); off += (size_t)12 * 74 * 4096 * 2;
    u16* W2hi = (u16*)(wsb + off); off += (size_t)12 * 16 * 8192 * 2;
    u16* W2lo = (u16*)(wsb + off); off += (size_t)12 * 16 * 8192 * 2;
    u16* zxb  = (u16*)(wsb + off);

    kprep_win<<<dim3(74, 12), 512, 0, stream>>>(t_Win, b_Win, W1hi, W1lo);
    kprep_wout<<<dim3(16, 12), 512, 0, stream>>>(t_Wout, t_gn, b_Wout, b_gn, W2hi, W2lo);

    const int NB = NTOK / 64;   // 1024 blocks for K1/K3

    for (int i = 0; i < NLAY; i++) {
        const float* src_t = (i == 0) ? x : out;
        // ---- time pass: 128 seqs x L=512, transposed store ----
        k1_mfma<<<NB, 512, 0, stream>>>(src_t, zxb, t_norm + i * Hd,
                 W1hi + (size_t)i * 74 * 4096, W1lo + (size_t)i * 74 * 4096);
        k2_scan<<<dim3(128, NHEADS), 64, 0, stream>>>(zxb,
                 t_cw + i * 4 * CONVDv, t_cb + i * CONVDv, t_dtb + i * NHEADS,
                 t_Alog + i * NHEADS, t_D + i * NHEADS, 512);
        k3_mfma<true><<<NB, 512, 0, stream>>>(zxb, src_t, xbuf,
                 W2hi + (size_t)i * 16 * 8192, W2lo + (size_t)i * 16 * 8192);
        // ---- band pass: 1024 seqs x L=64, identity store ----
        k1_mfma<<<NB, 512, 0, stream>>>(xbuf, zxb, b_norm + i * Hd,
                 W1hi + (size_t)(i + 6) * 74 * 4096, W1lo + (size_t)(i + 6) * 74 * 4096);
        k2_scan<<<dim3(1024, NHEADS), 64, 0, stream>>>(zxb,
                 b_cw + i * 4 * CONVDv, b_cb + i * CONVDv, b_dtb + i * NHEADS,
                 b_Alog + i * NHEADS, b_D + i * NHEADS, 64);
        k3_mfma<false><<<NB, 512, 0, stream>>>(zxb, xbuf, out,
                 W2hi + (size_t)(i + 6) * 16 * 8192, W2lo + (size_t)(i + 6) * 16 * 8192);
    }
}

// Round 6
// 8357.083 us; speedup vs baseline: 4.5780x; 1.5138x over previous
//
#include <hip/hip_runtime.h>
#include <math.h>

#define NLAY   6
#define Hd     256
#define DINv   512
#define NHEADS 8
#define CONVDv 640
#define PROJv  1160   // 2*DIN + 2*N + HEADS
#define PROJP  1184   // padded to 74 MFMA col-tiles
#define NTOK   65536
#define NCH    1024   // 64-token chunks

typedef __attribute__((ext_vector_type(8))) short bf16x8;
typedef __attribute__((ext_vector_type(4))) float f32x4;
typedef unsigned short u16;

__device__ __forceinline__ float siluf(float v) { return v / (1.0f + expf(-v)); }
__device__ __forceinline__ float bflo(unsigned u) { return __uint_as_float(u << 16); }
__device__ __forceinline__ float bfhi(unsigned u) { return __uint_as_float(u & 0xffff0000u); }
__device__ __forceinline__ u16 f2b(float f) {  // RNE fp32->bf16
    unsigned u = __float_as_uint(f);
    return (u16)((u + 0x7fffu + ((u >> 16) & 1u)) >> 16);
}
__device__ __forceinline__ float b2f(u16 s) { return __uint_as_float(((unsigned)s) << 16); }

__device__ __forceinline__ void gl_lds16(const void* g, void* l) {
    __builtin_amdgcn_global_load_lds((const __attribute__((address_space(1))) unsigned int*)g,
                                     (__attribute__((address_space(3))) unsigned int*)l, 16, 0, 0);
}

// ---------- prep: Win -> bf16 hi/lo, fragment order [li][j(74)][kk(8)][col(16)][quad(4)][e(8)] ----------
__global__ __launch_bounds__(512)
void kprep_win(const float* __restrict__ tW, const float* __restrict__ bW,
               u16* __restrict__ Whi, u16* __restrict__ Wlo)
{
    const int li = blockIdx.y, j = blockIdx.x;    // j 0..73
    const int t  = threadIdx.x;
    const int kk = t >> 6, col = (t >> 2) & 15, quad = t & 3;
    const float* W = (li < 6) ? (tW + (size_t)li * Hd * PROJv)
                              : (bW + (size_t)(li - 6) * Hd * PROJv);
    const int fullcol = 16 * j + col;
    const size_t ob = ((size_t)li * 74 + j) * 4096 + kk * 512 + col * 32 + quad * 8;
#pragma unroll
    for (int e = 0; e < 8; e++) {
        const int k = kk * 32 + quad * 8 + e;
        const float v = (fullcol < PROJv) ? W[(size_t)k * PROJv + fullcol] : 0.f;
        const u16 hi = f2b(v);
        Whi[ob + e] = hi;
        Wlo[ob + e] = f2b(v - b2f(hi));
    }
}

// ---------- prep: Wout*gn -> bf16 hi/lo, fragment order [li][j(16)][kk(16)][col(16)][quad(4)][e(8)] ----------
__global__ __launch_bounds__(512)
void kprep_wout(const float* __restrict__ tW, const float* __restrict__ tg,
                const float* __restrict__ bW, const float* __restrict__ bg,
                u16* __restrict__ Whi, u16* __restrict__ Wlo)
{
    const int li = blockIdx.y, j = blockIdx.x;    // j 0..15
    const int t  = threadIdx.x;
    const int kk = t >> 5, col = (t >> 1) & 15, qh = t & 1;
    const float* W = (li < 6) ? tW + (size_t)li * DINv * Hd : bW + (size_t)(li - 6) * DINv * Hd;
    const float* g = (li < 6) ? tg + li * DINv : bg + (li - 6) * DINv;
    const int fullcol = 16 * j + col;
#pragma unroll
    for (int q = 0; q < 2; q++) {
        const int quad = qh * 2 + q;
        const size_t ob = ((size_t)li * 16 + j) * 8192 + kk * 512 + col * 32 + quad * 8;
#pragma unroll
        for (int e = 0; e < 8; e++) {
            const int k = kk * 32 + quad * 8 + e;
            const float v = W[(size_t)k * Hd + fullcol] * g[k];
            const u16 hi = f2b(v);
            Whi[ob + e] = hi;
            Wlo[ob + e] = f2b(v - b2f(hi));
        }
    }
}

// ---------- K1: rmsnorm(x) @ Win -> zx bf16. 64 tok/block, overlaid LDS, bnd dup-store ----------
__global__ __launch_bounds__(512, 4)
void k1_mfma(const float* __restrict__ src, u16* __restrict__ zx,
             const float* __restrict__ nw,
             const u16* __restrict__ Whi, const u16* __restrict__ Wlo,
             u16* __restrict__ bnd)
{
    __shared__ __align__(16) char smem[67584];    // union: sA (66KB) then sW dbuf (64KB)
    u16* sAh = (u16*)smem;                        // 64*264
    u16* sAl = sAh + 64 * 264;
    const int tid = threadIdx.x;
    const int R0  = blockIdx.x * 64;

    { // phase A: load 64x256 fp32, rmsnorm, hi/lo -> LDS
        const int tok = tid >> 3, l8 = tid & 7;
        const float* xr = src + ((size_t)(R0 + tok)) * Hd + l8 * 32;
        float vv[32];
#pragma unroll
        for (int q = 0; q < 8; q++) {
            float4 v = ((const float4*)xr)[q];
            vv[4*q] = v.x; vv[4*q+1] = v.y; vv[4*q+2] = v.z; vv[4*q+3] = v.w;
        }
        float ss = 0.f;
#pragma unroll
        for (int j = 0; j < 32; j++) ss += vv[j] * vv[j];
#pragma unroll
        for (int m = 4; m >= 1; m >>= 1) ss += __shfl_xor(ss, m, 8);
        const float rstd = rsqrtf(ss * (1.0f / Hd) + 1e-6f);
        const float* nr = nw + l8 * 32;
        u16* dh = sAh + tok * 264 + l8 * 32;
        u16* dl = sAl + tok * 264 + l8 * 32;
#pragma unroll
        for (int j = 0; j < 32; j++) {
            const float val = vv[j] * rstd * nr[j];
            const u16 hi = f2b(val);
            dh[j] = hi;
            dl[j] = f2b(val - b2f(hi));
        }
    }
    __syncthreads();

    const int lane = tid & 63, wave = tid >> 6;
    const int rh = wave >> 1, cw = wave & 1;
    const int quad = lane >> 4, m16 = lane & 15;

    bf16x8 ah[8], al[8];
    {
        const u16* ph = sAh + (rh * 16 + m16) * 264 + quad * 8;
        const u16* pl = sAl + (rh * 16 + m16) * 264 + quad * 8;
#pragma unroll
        for (int kk = 0; kk < 8; kk++) {
            ah[kk] = *(const bf16x8*)(ph + kk * 32);
            al[kk] = *(const bf16x8*)(pl + kk * 32);
        }
    }
    __syncthreads();   // all frag reads done before sW overlays sA

    u16* sW = (u16*)smem;  // 2 bufs x 16384 u16 (pair: j0hi|j0lo|j1hi|j1lo, 8KB each)

#define K1_STAGE(p, buf)                                                          \
    {                                                                             \
        const int obase = wave * 4096;                                            \
        _Pragma("unroll")                                                         \
        for (int i = 0; i < 4; i++) {                                             \
            const int o = obase + i * 1024;                                       \
            const int chunk = o >> 13, t2 = chunk >> 1, hl = chunk & 1;           \
            const int within = o & 8191;                                          \
            const u16* sbase = (hl ? Wlo : Whi) + (size_t)(2 * (p) + t2) * 4096;  \
            gl_lds16((const char*)sbase + within + lane * 16,                     \
                     (char*)sW + (buf) * 32768 + o);                              \
        }                                                                         \
    }

    K1_STAGE(0, 0);
    __syncthreads();

    for (int p = 0; p < 37; p++) {
        if (p < 36) K1_STAGE(p + 1, (p + 1) & 1);
        const int j = 2 * p + cw;
        const u16* tb = sW + (p & 1) * 16384 + cw * 8192 + m16 * 32 + quad * 8;
        f32x4 acc = (f32x4){0.f, 0.f, 0.f, 0.f};
#pragma unroll
        for (int kk = 0; kk < 8; kk++) {
            bf16x8 bh = *(const bf16x8*)(tb + kk * 512);
            bf16x8 bl = *(const bf16x8*)(tb + 4096 + kk * 512);
            acc = __builtin_amdgcn_mfma_f32_16x16x32_bf16(ah[kk], bh, acc, 0, 0, 0);
            acc = __builtin_amdgcn_mfma_f32_16x16x32_bf16(al[kk], bh, acc, 0, 0, 0);
            acc = __builtin_amdgcn_mfma_f32_16x16x32_bf16(ah[kk], bl, acc, 0, 0, 0);
        }
        u16* zr = zx + (size_t)(R0 + rh * 16 + quad * 4) * PROJP + 16 * j + m16;
        const bool bndw = (j >= 32) && (j < 72) && (rh == 3) && (quad == 3);
#pragma unroll
        for (int i = 0; i < 4; i++) {
            const u16 v = f2b(acc[i]);
            zr[(size_t)i * PROJP] = v;
            if (bndw && i >= 1)   // rows R0+61..63 -> boundary buffer for conv
                bnd[((size_t)(R0 >> 6) * 3 + (i - 1)) * 640 + (16 * j + m16 - 512)] = v;
        }
        __syncthreads();
    }
#undef K1_STAGE
}

// ---------- K2a: causal conv4 + silu (in place over zx xBC cols) + softplus/dA -> spbuf ----------
__global__ __launch_bounds__(256, 4)
void k2a_conv(u16* __restrict__ zx, float* __restrict__ spb,
              const u16* __restrict__ bnd,
              const float* __restrict__ cwp, const float* __restrict__ cbp,
              const float* __restrict__ dtbp, const float* __restrict__ alogp,
              int L)
{
    const int tid = threadIdx.x;
    const int cb  = blockIdx.x;
    const size_t row0 = (size_t)cb * 64;
    const bool hasPrev = (((int)row0) % L) != 0;

    const bool has2 = tid < 128;
    const int c0 = tid, c1 = 256 + tid, c2 = 512 + tid;
    float w0[4], w1[4], w2[4] = {0,0,0,0};
    const float bia0 = cbp[c0], bia1 = cbp[c1];
    float bia2 = 0.f;
#pragma unroll
    for (int k = 0; k < 4; k++) { w0[k] = cwp[k*640 + c0]; w1[k] = cwp[k*640 + c1]; }
    if (has2) {
        bia2 = cbp[c2];
#pragma unroll
        for (int k = 0; k < 4; k++) w2[k] = cwp[k*640 + c2];
    }
    float win0[3] = {0,0,0}, win1[3] = {0,0,0}, win2[3] = {0,0,0};
    if (hasPrev) {
        const u16* bp = bnd + (size_t)(cb - 1) * 1920;
#pragma unroll
        for (int k = 0; k < 3; k++) {
            win0[k] = b2f(bp[k*640 + c0]);
            win1[k] = b2f(bp[k*640 + c1]);
            if (has2) win2[k] = b2f(bp[k*640 + c2]);
        }
    }
    const bool isdt = tid < NHEADS;
    const float dtb = isdt ? dtbp[tid] : 0.f;
    const float nA  = isdt ? -expf(alogp[tid]) : 0.f;

    const u16* bz = zx + row0 * PROJP;
    u16 p0 = bz[512 + c0], p1 = bz[512 + c1];
    u16 p2 = has2 ? bz[512 + c2] : (u16)0;
    u16 pd = isdt ? bz[1152 + tid] : (u16)0;

    for (int t = 0; t < 64; t++) {
        const size_t row = row0 + t;
        const u16 r0 = p0, r1 = p1, r2 = p2, rd = pd;
        if (t + 1 < 64) {
            const u16* nz = zx + (row + 1) * PROJP;
            p0 = nz[512 + c0]; p1 = nz[512 + c1];
            if (has2) p2 = nz[512 + c2];
            if (isdt) pd = nz[1152 + tid];
        }
        u16* wr = zx + row * PROJP;
        const float x0 = b2f(r0);
        const float v0 = siluf(bia0 + w0[0]*win0[0] + w0[1]*win0[1] + w0[2]*win0[2] + w0[3]*x0);
        win0[0] = win0[1]; win0[1] = win0[2]; win0[2] = x0;
        wr[512 + c0] = f2b(v0);
        const float x1 = b2f(r1);
        const float v1 = siluf(bia1 + w1[0]*win1[0] + w1[1]*win1[1] + w1[2]*win1[2] + w1[3]*x1);
        win1[0] = win1[1]; win1[1] = win1[2]; win1[2] = x1;
        wr[512 + c1] = f2b(v1);
        if (has2) {
            const float x2 = b2f(r2);
            const float v2 = siluf(bia2 + w2[0]*win2[0] + w2[1]*win2[1] + w2[2]*win2[2] + w2[3]*x2);
            win2[0] = win2[1]; win2[1] = win2[2]; win2[2] = x2;
            wr[512 + c2] = f2b(v2);
        }
        if (isdt) {
            const float dts = b2f(rd) + dtb;
            const float sp = (dts > 20.f) ? dts : log1pf(expf(dts));
            spb[row * 24 + tid] = sp;
            spb[row * 24 + 8 + tid] = expf(nA * sp);
        }
    }
}

// ---------- K2b phase1: per-chunk recurrent scan from h=0 ----------
// TMODE: write partial-y over xs cols, store S + acum. Band: gate+store directly.
template<bool TMODE>
__global__ __launch_bounds__(64, 4)
void k2b_scan(u16* __restrict__ zx, float* __restrict__ spb,
              u16* __restrict__ Sbuf, const float* __restrict__ Dp)
{
    __shared__ __align__(16) float sB[64];
    __shared__ __align__(16) float sC[64];
    const int p = threadIdx.x, h = blockIdx.y, cb = blockIdx.x;
    const size_t row0 = (size_t)cb * 64;
    const float Dh = Dp[h];
    const int cx = 512 + h * 64 + p;

    float hs[64];
#pragma unroll
    for (int n = 0; n < 64; n++) hs[n] = 0.f;
    float a = 1.f;

    const u16* bz = zx + row0 * PROJP;
    u16 px = bz[cx], pb = bz[1024 + p], pc = bz[1088 + p];
    u16 pz = TMODE ? (u16)0 : bz[h * 64 + p];
    float psp = spb[row0 * 24 + h], pdA = spb[row0 * 24 + 8 + h];

    for (int t = 0; t < 64; t++) {
        const size_t row = row0 + t;
        const u16 rx = px, rb = pb, rc = pc, rz = pz;
        const float sp = psp, dA = pdA;
        if (t + 1 < 64) {
            const u16* nz = zx + (row + 1) * PROJP;
            px = nz[cx]; pb = nz[1024 + p]; pc = nz[1088 + p];
            if (!TMODE) pz = nz[h * 64 + p];
            psp = spb[(row + 1) * 24 + h];
            pdA = spb[(row + 1) * 24 + 8 + h];
        }
        a *= dA;
        if (TMODE && p == 0) spb[row * 24 + 16 + h] = a;

        const float xv = b2f(rx);
        const float xdt = xv * sp;
        sB[p] = b2f(rb);
        sC[p] = b2f(rc);
        float y0 = 0.f, y1 = 0.f, y2 = 0.f, y3 = 0.f;
        const float4* B4 = (const float4*)sB;
        const float4* C4 = (const float4*)sC;
#pragma unroll
        for (int q = 0; q < 16; q++) {
            float4 bq = B4[q], cq = C4[q];
            hs[4*q+0] = fmaf(dA, hs[4*q+0], xdt * bq.x); y0 = fmaf(hs[4*q+0], cq.x, y0);
            hs[4*q+1] = fmaf(dA, hs[4*q+1], xdt * bq.y); y1 = fmaf(hs[4*q+1], cq.y, y1);
            hs[4*q+2] = fmaf(dA, hs[4*q+2], xdt * bq.z); y2 = fmaf(hs[4*q+2], cq.z, y2);
            hs[4*q+3] = fmaf(dA, hs[4*q+3], xdt * bq.w); y3 = fmaf(hs[4*q+3], cq.w, y3);
        }
        const float y = fmaf(Dh, xv, (y0 + y1) + (y2 + y3));
        if (TMODE) zx[row * PROJP + cx] = f2b(y);
        else       zx[row * PROJP + h * 64 + p] = f2b(y * siluf(b2f(rz)));
    }

    if (TMODE) {  // store chunk-final state S (bf16), layout [slot][p][n]
        u16* sp_ = Sbuf + (((size_t)cb * 8 + h) * 4096) + p * 64;
#pragma unroll
        for (int n = 0; n < 64; n += 8) {
            uint4 v;
            v.x = (unsigned)f2b(hs[n+0]) | ((unsigned)f2b(hs[n+1]) << 16);
            v.y = (unsigned)f2b(hs[n+2]) | ((unsigned)f2b(hs[n+3]) << 16);
            v.z = (unsigned)f2b(hs[n+4]) | ((unsigned)f2b(hs[n+5]) << 16);
            v.w = (unsigned)f2b(hs[n+6]) | ((unsigned)f2b(hs[n+7]) << 16);
            *(uint4*)(sp_ + n) = v;
        }
    }
}

// ---------- K2c phase2: combine chunk states (time pass). In-place S->H. ----------
// H_c (start state of chunk c) = P_{c-1} H_{c-1} + S_{c-1}, written over slot c-1.
__global__ __launch_bounds__(64, 4)
void k2c_states(u16* __restrict__ Sbuf, const float* __restrict__ spb)
{
    const int p = threadIdx.x, h = blockIdx.y, s = blockIdx.x;  // s 0..127
    float H[64];
#pragma unroll
    for (int n = 0; n < 64; n++) H[n] = 0.f;
    for (int c = 1; c < 8; c++) {
        const float P = spb[((size_t)s * 512 + (c - 1) * 64 + 63) * 24 + 16 + h];
        u16* sp_ = Sbuf + (((size_t)(s * 8 + c - 1) * 8 + h) * 4096) + p * 64;
#pragma unroll
        for (int n = 0; n < 64; n += 8) {
            uint4 v = *(const uint4*)(sp_ + n);
            unsigned uu[4] = {v.x, v.y, v.z, v.w};
            float sv[8];
#pragma unroll
            for (int w2 = 0; w2 < 4; w2++) { sv[2*w2] = bflo(uu[w2]); sv[2*w2+1] = bfhi(uu[w2]); }
#pragma unroll
            for (int e = 0; e < 8; e++) H[n + e] = fmaf(P, H[n + e], sv[e]);
            uint4 o;
            o.x = (unsigned)f2b(H[n+0]) | ((unsigned)f2b(H[n+1]) << 16);
            o.y = (unsigned)f2b(H[n+2]) | ((unsigned)f2b(H[n+3]) << 16);
            o.z = (unsigned)f2b(H[n+4]) | ((unsigned)f2b(H[n+5]) << 16);
            o.w = (unsigned)f2b(H[n+6]) | ((unsigned)f2b(H[n+7]) << 16);
            *(uint4*)(sp_ + n) = o;
        }
    }
}

// ---------- K2d phase3: y += a_t * (C_t . H), gate with silu(z), write over z cols ----------
__global__ __launch_bounds__(64, 4)
void k2d_corr(u16* __restrict__ zx, const float* __restrict__ spb,
              const u16* __restrict__ Sbuf)
{
    __shared__ __align__(16) float sCt[64 * 64];   // 16KB, [t][n] fp32
    const int p = threadIdx.x, h = blockIdx.y, cb = blockIdx.x;
    const int c = cb & 7;
    const size_t row0 = (size_t)cb * 64;

    { // load C chunk (thread p = row p)
        const u16* cr = zx + (row0 + p) * PROJP + 1088;
#pragma unroll
        for (int n = 0; n < 64; n += 8) {
            uint4 v = *(const uint4*)(cr + n);
            unsigned uu[4] = {v.x, v.y, v.z, v.w};
#pragma unroll
            for (int w2 = 0; w2 < 4; w2++) {
                sCt[p * 64 + n + 2*w2]     = bflo(uu[w2]);
                sCt[p * 64 + n + 2*w2 + 1] = bfhi(uu[w2]);
            }
        }
    }
    float H[64];
    if (c) {
        const u16* sp_ = Sbuf + (((size_t)(cb - 1) * 8 + h) * 4096) + p * 64;
#pragma unroll
        for (int n = 0; n < 64; n += 8) {
            uint4 v = *(const uint4*)(sp_ + n);
            unsigned uu[4] = {v.x, v.y, v.z, v.w};
#pragma unroll
            for (int w2 = 0; w2 < 4; w2++) { H[n+2*w2] = bflo(uu[w2]); H[n+2*w2+1] = bfhi(uu[w2]); }
        }
    } else {
#pragma unroll
        for (int n = 0; n < 64; n++) H[n] = 0.f;
    }
    __syncthreads();

    const int cy = 512 + h * 64 + p, cz = h * 64 + p;
    u16 py = zx[row0 * PROJP + cy], pz = zx[row0 * PROJP + cz];
    float pa = spb[row0 * 24 + 16 + h];

    for (int t = 0; t < 64; t++) {
        const size_t row = row0 + t;
        const u16 ry = py, rz = pz;
        const float at = pa;
        if (t + 1 < 64) {
            py = zx[(row + 1) * PROJP + cy];
            pz = zx[(row + 1) * PROJP + cz];
            pa = spb[(row + 1) * 24 + 16 + h];
        }
        float c0 = 0.f, c1 = 0.f, c2 = 0.f, c3 = 0.f;
        const float4* C4 = (const float4*)&sCt[t * 64];
#pragma unroll
        for (int q = 0; q < 16; q++) {
            float4 cq = C4[q];
            c0 = fmaf(cq.x, H[4*q+0], c0); c1 = fmaf(cq.y, H[4*q+1], c1);
            c2 = fmaf(cq.z, H[4*q+2], c2); c3 = fmaf(cq.w, H[4*q+3], c3);
        }
        const float y = b2f(ry) + at * ((c0 + c1) + (c2 + c3));
        zx[row * PROJP + cz] = f2b(y * siluf(b2f(rz)));
    }
}

// ---------- K3: rmsnorm(gated y) @ (gn*Wout) + residual. 128 tok/block, A in regs ----------
template<bool TMODE>
__global__ __launch_bounds__(512, 2)
void k3_mfma(const u16* __restrict__ zx, const float* __restrict__ src,
             float* __restrict__ dst,
             const u16* __restrict__ Whi, const u16* __restrict__ Wlo)
{
    __shared__ __align__(16) char smem[66560];   // max(32*516*4 = 66048, 2*32KB = 65536)
    float* sAf = (float*)smem;
    const int tid = threadIdx.x;
    const int R0  = blockIdx.x * 128;
    const int lane = tid & 63, wave = tid >> 6;
    const int quad = lane >> 4, m16 = lane & 15;

    bf16x8 ah[16], al[16];

    for (int b = 0; b < 4; b++) {
        { // cooperative load + rmsnorm of 32 rows -> sAf fp32 (stride 516)
            const int tok = tid >> 4, l16 = tid & 15;
            const u16* yr = zx + (size_t)(R0 + b * 32 + tok) * PROJP + l16 * 32;
            float v[32];
#pragma unroll
            for (int q = 0; q < 4; q++) {
                uint4 u = ((const uint4*)yr)[q];
                unsigned uu[4] = {u.x, u.y, u.z, u.w};
#pragma unroll
                for (int w2 = 0; w2 < 4; w2++) {
                    v[8*q + 2*w2]     = bflo(uu[w2]);
                    v[8*q + 2*w2 + 1] = bfhi(uu[w2]);
                }
            }
            float ss = 0.f;
#pragma unroll
            for (int j = 0; j < 32; j++) ss += v[j] * v[j];
#pragma unroll
            for (int m = 8; m >= 1; m >>= 1) ss += __shfl_xor(ss, m, 16);
            const float rstd = rsqrtf(ss * (1.0f / DINv) + 1e-6f);
            float* dp = sAf + tok * 516 + l16 * 32;
#pragma unroll
            for (int j = 0; j < 32; j++) dp[j] = v[j] * rstd;
        }
        __syncthreads();
        if ((wave >> 1) == b) {  // 2 waves own this batch's rows
            const int r = (wave & 1) * 16 + m16;
            const float* fp = sAf + r * 516 + quad * 8;
#pragma unroll
            for (int kk = 0; kk < 16; kk++) {
                float4 fa = ((const float4*)(fp + kk * 32))[0];
                float4 fb = ((const float4*)(fp + kk * 32))[1];
                float f[8] = {fa.x, fa.y, fa.z, fa.w, fb.x, fb.y, fb.z, fb.w};
                bf16x8 hv, lv;
#pragma unroll
                for (int e = 0; e < 8; e++) {
                    const u16 hi = f2b(f[e]);
                    hv[e] = (short)hi;
                    lv[e] = (short)f2b(f[e] - b2f(hi));
                }
                ah[kk] = hv;
                al[kk] = lv;
            }
        }
        __syncthreads();
    }

    f32x4 acc[16];
#pragma unroll
    for (int j = 0; j < 16; j++) acc[j] = (f32x4){0.f, 0.f, 0.f, 0.f};

#define K3_STAGE(j, buf)                                                          \
    {                                                                             \
        const int obase = wave * 4096;                                            \
        _Pragma("unroll")                                                         \
        for (int i = 0; i < 4; i++) {                                             \
            const int o = obase + i * 1024;                                       \
            const char* gsrc = (o < 16384)                                        \
                ? ((const char*)(Whi + (size_t)(j) * 8192) + o)                   \
                : ((const char*)(Wlo + (size_t)(j) * 8192) + (o - 16384));        \
            gl_lds16(gsrc + lane * 16, smem + (buf) * 32768 + o);                 \
        }                                                                         \
    }

    K3_STAGE(0, 0);
    __syncthreads();

    for (int j = 0; j < 16; j++) {
        if (j < 15) K3_STAGE(j + 1, (j + 1) & 1);
        const u16* tb = (const u16*)(smem + (j & 1) * 32768) + m16 * 32 + quad * 8;
#pragma unroll
        for (int kk = 0; kk < 16; kk++) {
            bf16x8 bh = *(const bf16x8*)(tb + kk * 512);
            bf16x8 bl = *(const bf16x8*)(tb + 8192 + kk * 512);
            acc[j] = __builtin_amdgcn_mfma_f32_16x16x32_bf16(ah[kk], bh, acc[j], 0, 0, 0);
            acc[j] = __builtin_amdgcn_mfma_f32_16x16x32_bf16(al[kk], bh, acc[j], 0, 0, 0);
            acc[j] = __builtin_amdgcn_mfma_f32_16x16x32_bf16(ah[kk], bl, acc[j], 0, 0, 0);
        }
        __syncthreads();
    }
#undef K3_STAGE

    // epilogue: + residual, store fp32 (transposed rows for time pass)
#pragma unroll
    for (int j = 0; j < 16; j++) {
        const int col = 16 * j + m16;
#pragma unroll
        for (int i = 0; i < 4; i++) {
            const size_t inrow = (size_t)(R0 + wave * 16 + quad * 4 + i);
            const float v = acc[j][i] + src[inrow * Hd + col];
            size_t orow;
            if (TMODE) {
                const size_t sq = inrow >> 9;
                const size_t tt = inrow & 511;
                orow = ((sq >> 6) * 512 + tt) * 64 + (sq & 63);
            } else {
                orow = inrow;
            }
            dst[orow * Hd + col] = v;
        }
    }
}

extern "C" void kernel_launch(void* const* d_in, const int* in_sizes, int n_in,
                              void* d_out, int out_size, void* d_ws, size_t ws_size,
                              hipStream_t stream) {
    const float* x      = (const float*)d_in[0];
    const float* t_norm = (const float*)d_in[1];
    const float* t_Win  = (const float*)d_in[2];
    const float* t_cw   = (const float*)d_in[3];
    const float* t_cb   = (const float*)d_in[4];
    const float* t_dtb  = (const float*)d_in[5];
    const float* t_Alog = (const float*)d_in[6];
    const float* t_D    = (const float*)d_in[7];
    const float* t_gn   = (const float*)d_in[8];
    const float* t_Wout = (const float*)d_in[9];
    const float* b_norm = (const float*)d_in[10];
    const float* b_Win  = (const float*)d_in[11];
    const float* b_cw   = (const float*)d_in[12];
    const float* b_cb   = (const float*)d_in[13];
    const float* b_dtb  = (const float*)d_in[14];
    const float* b_Alog = (const float*)d_in[15];
    const float* b_D    = (const float*)d_in[16];
    const float* b_gn   = (const float*)d_in[17];
    const float* b_Wout = (const float*)d_in[18];

    float* out = (float*)d_out;
    char*  wsb = (char*)d_ws;
    // ws layout (bytes):
    //   xbuf/Sbuf 67,108,864 | W1hi 7,274,496 | W1lo | W2hi 3,145,728 | W2lo |
    //   zx 155,189,248 | spbuf 6,291,456 | bnd 3,932,160   (total ~242 MB)
    float* xbuf = (float*)wsb;
    u16*   Sbuf = (u16*)wsb;                       // overlays xbuf (disjoint lifetimes)
    size_t off = 67108864;
    u16* W1hi = (u16*)(wsb + off); off += (size_t)12 * 74 * 4096 * 2;
    u16* W1lo = (u16*)(wsb + off); off += (size_t)12 * 74 * 4096 * 2;
    u16* W2hi = (u16*)(wsb + off); off += (size_t)12 * 16 * 8192 * 2;
    u16* W2lo = (u16*)(wsb + off); off += (size_t)12 * 16 * 8192 * 2;
    u16* zxb  = (u16*)(wsb + off); off += (size_t)NTOK * PROJP * 2;
    float* spb = (float*)(wsb + off); off += (size_t)NTOK * 24 * 4;
    u16* bnd  = (u16*)(wsb + off);

    kprep_win<<<dim3(74, 12), 512, 0, stream>>>(t_Win, b_Win, W1hi, W1lo);
    kprep_wout<<<dim3(16, 12), 512, 0, stream>>>(t_Wout, t_gn, b_Wout, b_gn, W2hi, W2lo);

    for (int i = 0; i < NLAY; i++) {
        const float* src_t = (i == 0) ? x : out;
        // ---- time pass: 128 seqs x L=512, transposed store ----
        k1_mfma<<<NTOK/64, 512, 0, stream>>>(src_t, zxb, t_norm + i * Hd,
                 W1hi + (size_t)i * 74 * 4096, W1lo + (size_t)i * 74 * 4096, bnd);
        k2a_conv<<<NCH, 256, 0, stream>>>(zxb, spb, bnd,
                 t_cw + i * 4 * CONVDv, t_cb + i * CONVDv, t_dtb + i * NHEADS,
                 t_Alog + i * NHEADS, 512);
        k2b_scan<true><<<dim3(NCH, NHEADS), 64, 0, stream>>>(zxb, spb, Sbuf,
                 t_D + i * NHEADS);
        k2c_states<<<dim3(128, NHEADS), 64, 0, stream>>>(Sbuf, spb);
        k2d_corr<<<dim3(NCH, NHEADS), 64, 0, stream>>>(zxb, spb, Sbuf);
        k3_mfma<true><<<NTOK/128, 512, 0, stream>>>(zxb, src_t, xbuf,
                 W2hi + (size_t)i * 16 * 8192, W2lo + (size_t)i * 16 * 8192);
        // ---- band pass: 1024 seqs x L=64 (single chunk), identity store ----
        k1_mfma<<<NTOK/64, 512, 0, stream>>>(xbuf, zxb, b_norm + i * Hd,
                 W1hi + (size_t)(i + 6) * 74 * 4096, W1lo + (size_t)(i + 6) * 74 * 4096, bnd);
        k2a_conv<<<NCH, 256, 0, stream>>>(zxb, spb, bnd,
                 b_cw + i * 4 * CONVDv, b_cb + i * CONVDv, b_dtb + i * NHEADS,
                 b_Alog + i * NHEADS, 64);
        k2b_scan<false><<<dim3(NCH, NHEADS), 64, 0, stream>>>(zxb, spb, Sbuf,
                 b_D + i * NHEADS);
        k3_mfma<false><<<NTOK/128, 512, 0, stream>>>(zxb, xbuf, out,
                 W2hi + (size_t)(i + 6) * 16 * 8192, W2lo + (size_t)(i + 6) * 16 * 8192);
    }
}

// Round 8
// 6262.758 us; speedup vs baseline: 6.1089x; 1.3344x over previous
//
#include <hip/hip_runtime.h>
#include <math.h>

#define NLAY   6
#define Hd     256
#define DINv   512
#define NHEADS 8
#define CONVDv 640
#define PROJv  1160   // 2*DIN + 2*N + HEADS
#define ZW     656    // zsmall row: z 512 | B 64 | C 64 | dt 8 | pad 8
#define NTOK   65536
#define NCH    1024   // 64-token chunks

typedef __attribute__((ext_vector_type(8))) short bf16x8;
typedef __attribute__((ext_vector_type(4))) float f32x4;
typedef unsigned short u16;

__device__ __forceinline__ float siluf(float v) { return v / (1.0f + expf(-v)); }
__device__ __forceinline__ float bflo(unsigned u) { return __uint_as_float(u << 16); }
__device__ __forceinline__ float bfhi(unsigned u) { return __uint_as_float(u & 0xffff0000u); }
__device__ __forceinline__ u16 f2b(float f) {  // RNE fp32->bf16
    unsigned u = __float_as_uint(f);
    return (u16)((u + 0x7fffu + ((u >> 16) & 1u)) >> 16);
}
__device__ __forceinline__ float b2f(u16 s) { return __uint_as_float(((unsigned)s) << 16); }

__device__ __forceinline__ void gl_lds16(const void* g, void* l) {
    __builtin_amdgcn_global_load_lds((const __attribute__((address_space(1))) unsigned int*)g,
                                     (__attribute__((address_space(3))) unsigned int*)l, 16, 0, 0);
}

// ---------- prep: Win -> bf16 hi/lo, fragment order [li][j(74)][kk(8)][col(16)][quad(4)][e(8)] ----------
__global__ __launch_bounds__(512)
void kprep_win(const float* __restrict__ tW, const float* __restrict__ bW,
               u16* __restrict__ Whi, u16* __restrict__ Wlo)
{
    const int li = blockIdx.y, j = blockIdx.x;    // j 0..73
    const int t  = threadIdx.x;
    const int kk = t >> 6, col = (t >> 2) & 15, quad = t & 3;
    const float* W = (li < 6) ? (tW + (size_t)li * Hd * PROJv)
                              : (bW + (size_t)(li - 6) * Hd * PROJv);
    const int fullcol = 16 * j + col;
    const size_t ob = ((size_t)li * 74 + j) * 4096 + kk * 512 + col * 32 + quad * 8;
#pragma unroll
    for (int e = 0; e < 8; e++) {
        const int k = kk * 32 + quad * 8 + e;
        const float v = (fullcol < PROJv) ? W[(size_t)k * PROJv + fullcol] : 0.f;
        const u16 hi = f2b(v);
        Whi[ob + e] = hi;
        Wlo[ob + e] = f2b(v - b2f(hi));
    }
}

// ---------- prep: Wout*gn -> bf16 hi/lo, fragment order [li][j(16)][kk(16)][col(16)][quad(4)][e(8)] ----------
__global__ __launch_bounds__(512)
void kprep_wout(const float* __restrict__ tW, const float* __restrict__ tg,
                const float* __restrict__ bW, const float* __restrict__ bg,
                u16* __restrict__ Whi, u16* __restrict__ Wlo)
{
    const int li = blockIdx.y, j = blockIdx.x;    // j 0..15
    const int t  = threadIdx.x;
    const int kk = t >> 5, col = (t >> 1) & 15, qh = t & 1;
    const float* W = (li < 6) ? tW + (size_t)li * DINv * Hd : bW + (size_t)(li - 6) * DINv * Hd;
    const float* g = (li < 6) ? tg + li * DINv : bg + (li - 6) * DINv;
    const int fullcol = 16 * j + col;
#pragma unroll
    for (int q = 0; q < 2; q++) {
        const int quad = qh * 2 + q;
        const size_t ob = ((size_t)li * 16 + j) * 8192 + kk * 512 + col * 32 + quad * 8;
#pragma unroll
        for (int e = 0; e < 8; e++) {
            const int k = kk * 32 + quad * 8 + e;
            const float v = W[(size_t)k * Hd + fullcol] * g[k];
            const u16 hi = f2b(v);
            Whi[ob + e] = hi;
            Wlo[ob + e] = f2b(v - b2f(hi));
        }
    }
}

// ---------- K1: rmsnorm(x) @ Win. z/B/C/dt -> zs rows; xs -> xrawT[p][t]; halo dup -> bnd ----------
__global__ __launch_bounds__(512, 4)
void k1_mfma(const float* __restrict__ src, u16* __restrict__ zs,
             u16* __restrict__ xrawT, u16* __restrict__ bnd,
             const float* __restrict__ nw,
             const u16* __restrict__ Whi, const u16* __restrict__ Wlo)
{
    __shared__ __align__(16) char smem[67584];    // union: sA (66KB) then sW dbuf (64KB)
    u16* sAh = (u16*)smem;                        // 64*264
    u16* sAl = sAh + 64 * 264;
    const int tid = threadIdx.x;
    const int cb  = blockIdx.x;
    const int R0  = cb * 64;

    { // phase A: load 64x256 fp32, rmsnorm, hi/lo -> LDS
        const int tok = tid >> 3, l8 = tid & 7;
        const float* xr = src + ((size_t)(R0 + tok)) * Hd + l8 * 32;
        float vv[32];
#pragma unroll
        for (int q = 0; q < 8; q++) {
            float4 v = ((const float4*)xr)[q];
            vv[4*q] = v.x; vv[4*q+1] = v.y; vv[4*q+2] = v.z; vv[4*q+3] = v.w;
        }
        float ss = 0.f;
#pragma unroll
        for (int j = 0; j < 32; j++) ss += vv[j] * vv[j];
#pragma unroll
        for (int m = 4; m >= 1; m >>= 1) ss += __shfl_xor(ss, m, 8);
        const float rstd = rsqrtf(ss * (1.0f / Hd) + 1e-6f);
        const float* nr = nw + l8 * 32;
        u16* dh = sAh + tok * 264 + l8 * 32;
        u16* dl = sAl + tok * 264 + l8 * 32;
#pragma unroll
        for (int j = 0; j < 32; j++) {
            const float val = vv[j] * rstd * nr[j];
            const u16 hi = f2b(val);
            dh[j] = hi;
            dl[j] = f2b(val - b2f(hi));
        }
    }
    __syncthreads();

    const int lane = tid & 63, wave = tid >> 6;
    const int rh = wave >> 1, cw = wave & 1;
    const int quad = lane >> 4, m16 = lane & 15;

    bf16x8 ah[8], al[8];
    {
        const u16* ph = sAh + (rh * 16 + m16) * 264 + quad * 8;
        const u16* pl = sAl + (rh * 16 + m16) * 264 + quad * 8;
#pragma unroll
        for (int kk = 0; kk < 8; kk++) {
            ah[kk] = *(const bf16x8*)(ph + kk * 32);
            al[kk] = *(const bf16x8*)(pl + kk * 32);
        }
    }
    __syncthreads();   // all frag reads done before sW overlays sA

    u16* sW = (u16*)smem;  // 2 bufs x 16384 u16

#define K1_STAGE(p, buf)                                                          \
    {                                                                             \
        const int obase = wave * 4096;                                            \
        _Pragma("unroll")                                                         \
        for (int i = 0; i < 4; i++) {                                             \
            const int o = obase + i * 1024;                                       \
            const int chunk = o >> 13, t2 = chunk >> 1, hl = chunk & 1;           \
            const int within = o & 8191;                                          \
            const u16* sbase = (hl ? Wlo : Whi) + (size_t)(2 * (p) + t2) * 4096;  \
            gl_lds16((const char*)sbase + within + lane * 16,                     \
                     (char*)sW + (buf) * 32768 + o);                              \
        }                                                                         \
    }

    K1_STAGE(0, 0);
    __syncthreads();

    for (int p = 0; p < 37; p++) {
        if (p < 36) K1_STAGE(p + 1, (p + 1) & 1);
        const int j = 2 * p + cw;
        const u16* tb = sW + (p & 1) * 16384 + cw * 8192 + m16 * 32 + quad * 8;
        f32x4 acc = (f32x4){0.f, 0.f, 0.f, 0.f};
#pragma unroll
        for (int kk = 0; kk < 8; kk++) {
            bf16x8 bh = *(const bf16x8*)(tb + kk * 512);
            bf16x8 bl = *(const bf16x8*)(tb + 4096 + kk * 512);
            acc = __builtin_amdgcn_mfma_f32_16x16x32_bf16(ah[kk], bh, acc, 0, 0, 0);
            acc = __builtin_amdgcn_mfma_f32_16x16x32_bf16(al[kk], bh, acc, 0, 0, 0);
            acc = __builtin_amdgcn_mfma_f32_16x16x32_bf16(ah[kk], bl, acc, 0, 0, 0);
        }
        const int fullcol = 16 * j + m16;
        if (j < 32) {                         // z columns
            u16* zr = zs + (size_t)(R0 + rh * 16 + quad * 4) * ZW + fullcol;
#pragma unroll
            for (int i = 0; i < 4; i++) zr[(size_t)i * ZW] = f2b(acc[i]);
        } else if (j < 64) {                  // xs -> xrawT [ch][t], packed 4 u16
            const int ch = fullcol - 512;
            uint2 v;
            v.x = (unsigned)f2b(acc[0]) | ((unsigned)f2b(acc[1]) << 16);
            v.y = (unsigned)f2b(acc[2]) | ((unsigned)f2b(acc[3]) << 16);
            *(uint2*)(xrawT + ((size_t)cb * 512 + ch) * 64 + rh * 16 + quad * 4) = v;
            if (rh == 3 && quad == 3) {       // rows 61..63 halo dup
#pragma unroll
                for (int i = 1; i < 4; i++)
                    bnd[((size_t)cb * 3 + (i - 1)) * 640 + ch] = f2b(acc[i]);
            }
        } else if (j < 73) {                  // B/C/dt columns (zs col = fullcol-512)
            const int zc = fullcol - 512;
            u16* zr = zs + (size_t)(R0 + rh * 16 + quad * 4) * ZW + zc;
#pragma unroll
            for (int i = 0; i < 4; i++) zr[(size_t)i * ZW] = f2b(acc[i]);
            if (j < 72 && rh == 3 && quad == 3) {
#pragma unroll
                for (int i = 1; i < 4; i++)
                    bnd[((size_t)cb * 3 + (i - 1)) * 640 + zc] = f2b(acc[i]);
            }
        }
        __syncthreads();
    }
#undef K1_STAGE
}

// ---------- K2a: in-place conv4+silu (xs in xrawT, B/C in zs); softplus/logdA -> spb ----------
__global__ __launch_bounds__(256, 4)
void k2a_conv(u16* __restrict__ zs, u16* __restrict__ xrawT,
              float* __restrict__ spb, const u16* __restrict__ bnd,
              const float* __restrict__ cwp, const float* __restrict__ cbp,
              const float* __restrict__ dtbp, const float* __restrict__ alogp, int L)
{
    const int tid = threadIdx.x;
    const int cb  = blockIdx.x;
    const size_t row0 = (size_t)cb * 64;
    const bool atStart = (((int)(row0 % (size_t)L)) == 0);

    // xs channels: ch = tid, tid+256  (contiguous 64-t rows of xrawT, in place)
#pragma unroll
    for (int cc = 0; cc < 2; cc++) {
        const int ch = tid + cc * 256;
        const float w0 = cwp[0*CONVDv + ch], w1 = cwp[1*CONVDv + ch],
                    w2 = cwp[2*CONVDv + ch], w3 = cwp[3*CONVDv + ch];
        const float bias = cbp[ch];
        float h1 = 0.f, h2 = 0.f, h3 = 0.f;
        if (!atStart) {
            const u16* bp = bnd + ((size_t)(cb - 1) * 3) * 640 + ch;
            h3 = b2f(bp[0]);          // t-3 = row 61
            h2 = b2f(bp[640]);        // t-2 = row 62
            h1 = b2f(bp[1280]);       // t-1 = row 63
        }
        u16* xp = xrawT + ((size_t)cb * 512 + ch) * 64;
#pragma unroll
        for (int seg = 0; seg < 4; seg++) {
            uint4 a = ((const uint4*)xp)[seg * 2];
            uint4 b = ((const uint4*)xp)[seg * 2 + 1];
            unsigned uu[8] = {a.x, a.y, a.z, a.w, b.x, b.y, b.z, b.w};
            float in[16];
#pragma unroll
            for (int k = 0; k < 8; k++) { in[2*k] = bflo(uu[k]); in[2*k+1] = bfhi(uu[k]); }
            u16 o[16];
#pragma unroll
            for (int t = 0; t < 16; t++) {
                const float xv = in[t];
                o[t] = f2b(siluf(bias + w0*h3 + w1*h2 + w2*h1 + w3*xv));
                h3 = h2; h2 = h1; h1 = xv;
            }
            uint4 oa, ob;
            oa.x = o[0] | ((unsigned)o[1] << 16);   oa.y = o[2] | ((unsigned)o[3] << 16);
            oa.z = o[4] | ((unsigned)o[5] << 16);   oa.w = o[6] | ((unsigned)o[7] << 16);
            ob.x = o[8] | ((unsigned)o[9] << 16);   ob.y = o[10] | ((unsigned)o[11] << 16);
            ob.z = o[12] | ((unsigned)o[13] << 16); ob.w = o[14] | ((unsigned)o[15] << 16);
            ((uint4*)xp)[seg * 2] = oa;
            ((uint4*)xp)[seg * 2 + 1] = ob;
        }
    }

    // B/C channels (zs cols 512..639), in place
    if (tid < 128) {
        const int ch = 512 + tid;                 // xBC channel == zs col
        const float w0 = cwp[0*CONVDv + ch], w1 = cwp[1*CONVDv + ch],
                    w2 = cwp[2*CONVDv + ch], w3 = cwp[3*CONVDv + ch];
        const float bias = cbp[ch];
        float h1 = 0.f, h2 = 0.f, h3 = 0.f;
        if (!atStart) {
            const u16* bp = bnd + ((size_t)(cb - 1) * 3) * 640 + ch;
            h3 = b2f(bp[0]); h2 = b2f(bp[640]); h1 = b2f(bp[1280]);
        }
        u16* zp = zs + row0 * ZW + ch;
        for (int t = 0; t < 64; t++) {
            const float xv = b2f(zp[(size_t)t * ZW]);
            zp[(size_t)t * ZW] = f2b(siluf(bias + w0*h3 + w1*h2 + w2*h1 + w3*xv));
            h3 = h2; h2 = h1; h1 = xv;
        }
    }

    // dt -> softplus, log dA
    if (tid < NHEADS) {
        const float dtb = dtbp[tid], nA = -expf(alogp[tid]);
        const u16* dp = zs + row0 * ZW + 640 + tid;
        for (int t = 0; t < 64; t++) {
            const float dts = b2f(dp[(size_t)t * ZW]) + dtb;
            const float sp = (dts > 20.f) ? dts : log1pf(expf(dts));
            spb[(row0 + t) * 24 + tid] = sp;
            spb[(row0 + t) * 24 + 8 + tid] = nA * sp;
        }
    }
}

// ---------- K2b: SSD chunk kernel. G=C·B^T; S^T (TMODE, first); Y=M·X (over X) ----------
template<bool TMODE>
__global__ __launch_bounds__(256, 3)
void k2b_ssd(u16* __restrict__ zs, u16* __restrict__ xrawT,
             float* __restrict__ spb, u16* __restrict__ Sbuf,
             const float* __restrict__ Dp)
{
    __shared__ __align__(16) float sG[64][68];     // 17408 B
    __shared__ float sClog[NHEADS][64];            // 2048 B
    __shared__ float sSp[NHEADS][64];
    __shared__ float sWd[NHEADS][64];
    __shared__ __align__(16) u16 sBT[64][72];      // 9216 B (B transposed [n][t])
    const int tid = threadIdx.x;
    const int lane = tid & 63, wave = tid >> 6;
    const int quad = lane >> 4, m16 = lane & 15;
    const int cb = blockIdx.x;
    const size_t row0 = (size_t)cb * 64;

    if (TMODE) {   // B -> sBT transposed
        const int t_ = tid >> 2, ns = (tid & 3) * 16;
        const u16* br = zs + (row0 + t_) * ZW + 512 + ns;
        uint4 a = ((const uint4*)br)[0], b = ((const uint4*)br)[1];
        unsigned uu[8] = {a.x, a.y, a.z, a.w, b.x, b.y, b.z, b.w};
#pragma unroll
        for (int k = 0; k < 8; k++) {
            sBT[ns + 2*k][t_]     = (u16)(uu[k] & 0xffff);
            sBT[ns + 2*k + 1][t_] = (u16)(uu[k] >> 16);
        }
    }

    // --- G = C B^T : wave computes t-rows [16w,16w+16), all 4 s-tiles ---
    {
        const u16* cp = zs + (row0 + 16 * wave + m16) * ZW + 576 + quad * 8;
        bf16x8 cf0 = *(const bf16x8*)(cp);
        bf16x8 cf1 = *(const bf16x8*)(cp + 32);
#pragma unroll
        for (int st = 0; st < 4; st++) {
            const u16* bp = zs + (row0 + 16 * st + m16) * ZW + 512 + quad * 8;
            f32x4 acc = (f32x4){0.f, 0.f, 0.f, 0.f};
            acc = __builtin_amdgcn_mfma_f32_16x16x32_bf16(cf0, *(const bf16x8*)(bp), acc, 0, 0, 0);
            acc = __builtin_amdgcn_mfma_f32_16x16x32_bf16(cf1, *(const bf16x8*)(bp + 32), acc, 0, 0, 0);
#pragma unroll
            for (int i = 0; i < 4; i++)
                sG[16 * wave + quad * 4 + i][16 * st + m16] = acc[i];
        }
    }

    // --- inclusive cumsum of log dA; wave handles heads 2w, 2w+1 (lane = t) ---
#pragma unroll
    for (int hh = 0; hh < 2; hh++) {
        const int h = wave * 2 + hh;
        float c = spb[(row0 + lane) * 24 + 8 + h];
        const float sp = spb[(row0 + lane) * 24 + h];
#pragma unroll
        for (int d = 1; d < 64; d <<= 1) {
            const float o = __shfl_up(c, d, 64);
            if (lane >= d) c += o;
        }
        sClog[h][lane] = c;
        sSp[h][lane] = sp;
        if (TMODE) {
            spb[(row0 + lane) * 24 + 16 + h] = __expf(c);
            const float cl63 = __shfl(c, 63, 64);
            sWd[h][lane] = __expf(cl63 - c) * sp;
        }
    }
    __syncthreads();

    if (TMODE) {
        // --- S phase (before Y overwrites X): S^T[p][n] = sum_t (w_t x_t[p]) B_t[n] ---
        for (int h = 0; h < NHEADS; h++) {
            bf16x8 Ahi[2], Alo[2];
#pragma unroll
            for (int kk = 0; kk < 2; kk++) {
                const u16* xp = xrawT + ((size_t)cb * 512 + h * 64 + 16 * wave + m16) * 64
                                + 32 * kk + quad * 8;
                bf16x8 xf = *(const bf16x8*)xp;
                const float* wp = &sWd[h][32 * kk + quad * 8];
#pragma unroll
                for (int j = 0; j < 8; j++) {
                    const float v = b2f((u16)xf[j]) * wp[j];
                    const u16 hi = f2b(v);
                    Ahi[kk][j] = (short)hi;
                    Alo[kk][j] = (short)f2b(v - b2f(hi));
                }
            }
            u16* sb = Sbuf + ((size_t)cb * 8 + h) * 4096;
#pragma unroll
            for (int nt = 0; nt < 4; nt++) {
                f32x4 acc = (f32x4){0.f, 0.f, 0.f, 0.f};
#pragma unroll
                for (int kk = 0; kk < 2; kk++) {
                    const bf16x8 bf_ = *(const bf16x8*)(&sBT[16 * nt + m16][32 * kk + quad * 8]);
                    acc = __builtin_amdgcn_mfma_f32_16x16x32_bf16(Ahi[kk], bf_, acc, 0, 0, 0);
                    acc = __builtin_amdgcn_mfma_f32_16x16x32_bf16(Alo[kk], bf_, acc, 0, 0, 0);
                }
#pragma unroll
                for (int i = 0; i < 4; i++)
                    sb[(16 * wave + quad * 4 + i) * 64 + 16 * nt + m16] = f2b(acc[i]);
            }
        }
        __syncthreads();   // all X reads (S phase) complete before Y stores
    }

    // --- Y phase: Y = M·X ; TMODE stores Y^T over X in xrawT; band gates into z cols ---
    const int t = 16 * wave + m16;
    for (int h = 0; h < NHEADS; h++) {
        const float Dh = Dp[h];
        const float clt = sClog[h][t];
        bf16x8 Mhi[2], Mlo[2];
#pragma unroll
        for (int kk = 0; kk < 2; kk++) {
            const float* gp = &sG[t][32 * kk + quad * 8];
            const float* cp = &sClog[h][32 * kk + quad * 8];
            const float* pp = &sSp[h][32 * kk + quad * 8];
#pragma unroll
            for (int j = 0; j < 8; j++) {
                const int s = 32 * kk + quad * 8 + j;
                float m = (s <= t) ? (__expf(clt - cp[j]) * pp[j] * gp[j]) : 0.f;
                if (s == t) m += Dh;
                const u16 hi = f2b(m);
                Mhi[kk][j] = (short)hi;
                Mlo[kk][j] = (short)f2b(m - b2f(hi));
            }
        }
        bf16x8 xf[4][2];
#pragma unroll
        for (int pt = 0; pt < 4; pt++)
#pragma unroll
            for (int kk = 0; kk < 2; kk++)
                xf[pt][kk] = *(const bf16x8*)(xrawT
                    + ((size_t)cb * 512 + h * 64 + 16 * pt + m16) * 64 + 32 * kk + quad * 8);
        if (TMODE) __syncthreads();   // all waves loaded head h's X before any store
        f32x4 accY[4];
#pragma unroll
        for (int pt = 0; pt < 4; pt++) {
            accY[pt] = (f32x4){0.f, 0.f, 0.f, 0.f};
#pragma unroll
            for (int kk = 0; kk < 2; kk++) {
                accY[pt] = __builtin_amdgcn_mfma_f32_16x16x32_bf16(Mhi[kk], xf[pt][kk], accY[pt], 0, 0, 0);
                accY[pt] = __builtin_amdgcn_mfma_f32_16x16x32_bf16(Mlo[kk], xf[pt][kk], accY[pt], 0, 0, 0);
            }
        }
#pragma unroll
        for (int pt = 0; pt < 4; pt++) {
            if (TMODE) {   // Y^T[p][t], packed 4 u16 (t = 16w+quad*4+i)
                uint2 v;
                v.x = (unsigned)f2b(accY[pt][0]) | ((unsigned)f2b(accY[pt][1]) << 16);
                v.y = (unsigned)f2b(accY[pt][2]) | ((unsigned)f2b(accY[pt][3]) << 16);
                *(uint2*)(xrawT + ((size_t)cb * 512 + h * 64 + 16 * pt + m16) * 64
                          + 16 * wave + quad * 4) = v;
            } else {       // gate with silu(z), store into z cols (row-major for K3)
#pragma unroll
                for (int i = 0; i < 4; i++) {
                    const size_t row = row0 + 16 * wave + quad * 4 + i;
                    const int col = h * 64 + 16 * pt + m16;
                    const u16 zv = zs[row * ZW + col];
                    zs[row * ZW + col] = f2b(accY[pt][i] * siluf(b2f(zv)));
                }
            }
        }
    }
}

// ---------- K2c: combine chunk states (time pass). In-place S->H. ----------
__global__ __launch_bounds__(64, 4)
void k2c_states(u16* __restrict__ Sbuf, const float* __restrict__ spb)
{
    const int p = threadIdx.x, h = blockIdx.y, s = blockIdx.x;  // s 0..127
    float H[64];
#pragma unroll
    for (int n = 0; n < 64; n++) H[n] = 0.f;
    for (int c = 1; c < 8; c++) {
        const float P = spb[((size_t)s * 512 + (c - 1) * 64 + 63) * 24 + 16 + h];
        u16* sp_ = Sbuf + (((size_t)(s * 8 + c - 1) * 8 + h) * 4096) + p * 64;
#pragma unroll
        for (int n = 0; n < 64; n += 8) {
            uint4 v = *(const uint4*)(sp_ + n);
            unsigned uu[4] = {v.x, v.y, v.z, v.w};
            float sv[8];
#pragma unroll
            for (int w2 = 0; w2 < 4; w2++) { sv[2*w2] = bflo(uu[w2]); sv[2*w2+1] = bfhi(uu[w2]); }
#pragma unroll
            for (int e = 0; e < 8; e++) H[n + e] = fmaf(P, H[n + e], sv[e]);
            uint4 o;
            o.x = (unsigned)f2b(H[n+0]) | ((unsigned)f2b(H[n+1]) << 16);
            o.y = (unsigned)f2b(H[n+2]) | ((unsigned)f2b(H[n+3]) << 16);
            o.z = (unsigned)f2b(H[n+4]) | ((unsigned)f2b(H[n+5]) << 16);
            o.w = (unsigned)f2b(H[n+6]) | ((unsigned)f2b(H[n+7]) << 16);
            *(uint4*)(sp_ + n) = o;
        }
    }
}

// ---------- K2d: Y += diag(a)·C·H, gate with silu(z), write rows into zs z cols ----------
__global__ __launch_bounds__(256, 4)
void k2d_corr(u16* __restrict__ zs, const u16* __restrict__ xrawT,
              const float* __restrict__ spb, const u16* __restrict__ Sbuf)
{
    const int tid = threadIdx.x;
    const int lane = tid & 63, wave = tid >> 6;
    const int quad = lane >> 4, m16 = lane & 15;
    const int cb = blockIdx.x;
    const int c = cb & 7;
    const size_t row0 = (size_t)cb * 64;

    for (int h = 0; h < NHEADS; h++) {
        f32x4 acc[4];
#pragma unroll
        for (int pt = 0; pt < 4; pt++) {   // partial Y from xrawT [p][t]
            const uint2 v = *(const uint2*)(xrawT
                + ((size_t)cb * 512 + h * 64 + 16 * pt + m16) * 64 + 16 * wave + quad * 4);
            acc[pt][0] = bflo(v.x); acc[pt][1] = bfhi(v.x);
            acc[pt][2] = bflo(v.y); acc[pt][3] = bfhi(v.y);
        }
        if (c) {
            const float at = spb[(row0 + 16 * wave + m16) * 24 + 16 + h];
            bf16x8 Ahi[2], Alo[2];
#pragma unroll
            for (int kk = 0; kk < 2; kk++) {
                const u16* cp = zs + (row0 + 16 * wave + m16) * ZW + 576 + 32 * kk + quad * 8;
                bf16x8 cf = *(const bf16x8*)cp;
#pragma unroll
                for (int j = 0; j < 8; j++) {
                    const float v = b2f((u16)cf[j]) * at;
                    const u16 hi = f2b(v);
                    Ahi[kk][j] = (short)hi;
                    Alo[kk][j] = (short)f2b(v - b2f(hi));
                }
            }
            const u16* hb = Sbuf + ((size_t)(cb - 1) * 8 + h) * 4096;
#pragma unroll
            for (int pt = 0; pt < 4; pt++) {
#pragma unroll
                for (int kk = 0; kk < 2; kk++) {
                    bf16x8 hf = *(const bf16x8*)(hb + (16 * pt + m16) * 64 + 32 * kk + quad * 8);
                    acc[pt] = __builtin_amdgcn_mfma_f32_16x16x32_bf16(Ahi[kk], hf, acc[pt], 0, 0, 0);
                    acc[pt] = __builtin_amdgcn_mfma_f32_16x16x32_bf16(Alo[kk], hf, acc[pt], 0, 0, 0);
                }
            }
        }
#pragma unroll
        for (int pt = 0; pt < 4; pt++) {
#pragma unroll
            for (int i = 0; i < 4; i++) {
                const size_t row = row0 + 16 * wave + quad * 4 + i;
                const int col = h * 64 + 16 * pt + m16;
                const u16 zv = zs[row * ZW + col];
                zs[row * ZW + col] = f2b(acc[pt][i] * siluf(b2f(zv)));
            }
        }
    }
}

// ---------- K3: rmsnorm(gated y) @ (gn*Wout) + residual. 128 tok/block, A in regs ----------
template<bool TMODE>
__global__ __launch_bounds__(512, 2)
void k3_mfma(const u16* __restrict__ zs, const float* __restrict__ src,
             float* __restrict__ dst,
             const u16* __restrict__ Whi, const u16* __restrict__ Wlo)
{
    __shared__ __align__(16) char smem[66560];   // max(32*516*4, 2*32KB)
    float* sAf = (float*)smem;
    const int tid = threadIdx.x;
    const int R0  = blockIdx.x * 128;
    const int lane = tid & 63, wave = tid >> 6;
    const int quad = lane >> 4, m16 = lane & 15;

    bf16x8 ah[16], al[16];

    for (int b = 0; b < 4; b++) {
        {
            const int tok = tid >> 4, l16 = tid & 15;
            const u16* yr = zs + (size_t)(R0 + b * 32 + tok) * ZW + l16 * 32;
            float v[32];
#pragma unroll
            for (int q = 0; q < 4; q++) {
                uint4 u = ((const uint4*)yr)[q];
                unsigned uu[4] = {u.x, u.y, u.z, u.w};
#pragma unroll
                for (int w2 = 0; w2 < 4; w2++) {
                    v[8*q + 2*w2]     = bflo(uu[w2]);
                    v[8*q + 2*w2 + 1] = bfhi(uu[w2]);
                }
            }
            float ss = 0.f;
#pragma unroll
            for (int j = 0; j < 32; j++) ss += v[j] * v[j];
#pragma unroll
            for (int m = 8; m >= 1; m >>= 1) ss += __shfl_xor(ss, m, 16);
            const float rstd = rsqrtf(ss * (1.0f / DINv) + 1e-6f);
            float* dp = sAf + tok * 516 + l16 * 32;
#pragma unroll
            for (int j = 0; j < 32; j++) dp[j] = v[j] * rstd;
        }
        __syncthreads();
        if ((wave >> 1) == b) {
            const int r = (wave & 1) * 16 + m16;
            const float* fp = sAf + r * 516 + quad * 8;
#pragma unroll
            for (int kk = 0; kk < 16; kk++) {
                float4 fa = ((const float4*)(fp + kk * 32))[0];
                float4 fb = ((const float4*)(fp + kk * 32))[1];
                float f[8] = {fa.x, fa.y, fa.z, fa.w, fb.x, fb.y, fb.z, fb.w};
                bf16x8 hv, lv;
#pragma unroll
                for (int e = 0; e < 8; e++) {
                    const u16 hi = f2b(f[e]);
                    hv[e] = (short)hi;
                    lv[e] = (short)f2b(f[e] - b2f(hi));
                }
                ah[kk] = hv;
                al[kk] = lv;
            }
        }
        __syncthreads();
    }

    f32x4 acc[16];
#pragma unroll
    for (int j = 0; j < 16; j++) acc[j] = (f32x4){0.f, 0.f, 0.f, 0.f};

#define K3_STAGE(j, buf)                                                          \
    {                                                                             \
        const int obase = wave * 4096;                                            \
        _Pragma("unroll")                                                         \
        for (int i = 0; i < 4; i++) {                                             \
            const int o = obase + i * 1024;                                       \
            const char* gsrc = (o < 16384)                                        \
                ? ((const char*)(Whi + (size_t)(j) * 8192) + o)                   \
                : ((const char*)(Wlo + (size_t)(j) * 8192) + (o - 16384));        \
            gl_lds16(gsrc + lane * 16, smem + (buf) * 32768 + o);                 \
        }                                                                         \
    }

    K3_STAGE(0, 0);
    __syncthreads();

    for (int j = 0; j < 16; j++) {
        if (j < 15) K3_STAGE(j + 1, (j + 1) & 1);
        const u16* tb = (const u16*)(smem + (j & 1) * 32768) + m16 * 32 + quad * 8;
#pragma unroll
        for (int kk = 0; kk < 16; kk++) {
            bf16x8 bh = *(const bf16x8*)(tb + kk * 512);
            bf16x8 bl = *(const bf16x8*)(tb + 8192 + kk * 512);
            acc[j] = __builtin_amdgcn_mfma_f32_16x16x32_bf16(ah[kk], bh, acc[j], 0, 0, 0);
            acc[j] = __builtin_amdgcn_mfma_f32_16x16x32_bf16(al[kk], bh, acc[j], 0, 0, 0);
            acc[j] = __builtin_amdgcn_mfma_f32_16x16x32_bf16(ah[kk], bl, acc[j], 0, 0, 0);
        }
        __syncthreads();
    }
#undef K3_STAGE

#pragma unroll
    for (int j = 0; j < 16; j++) {
        const int col = 16 * j + m16;
#pragma unroll
        for (int i = 0; i < 4; i++) {
            const size_t inrow = (size_t)(R0 + wave * 16 + quad * 4 + i);
            const float v = acc[j][i] + src[inrow * Hd + col];
            size_t orow;
            if (TMODE) {
                const size_t sq = inrow >> 9;
                const size_t tt = inrow & 511;
                orow = ((sq >> 6) * 512 + tt) * 64 + (sq & 63);
            } else {
                orow = inrow;
            }
            dst[orow * Hd + col] = v;
        }
    }
}

extern "C" void kernel_launch(void* const* d_in, const int* in_sizes, int n_in,
                              void* d_out, int out_size, void* d_ws, size_t ws_size,
                              hipStream_t stream) {
    const float* x      = (const float*)d_in[0];
    const float* t_norm = (const float*)d_in[1];
    const float* t_Win  = (const float*)d_in[2];
    const float* t_cw   = (const float*)d_in[3];
    const float* t_cb   = (const float*)d_in[4];
    const float* t_dtb  = (const float*)d_in[5];
    const float* t_Alog = (const float*)d_in[6];
    const float* t_D    = (const float*)d_in[7];
    const float* t_gn   = (const float*)d_in[8];
    const float* t_Wout = (const float*)d_in[9];
    const float* b_norm = (const float*)d_in[10];
    const float* b_Win  = (const float*)d_in[11];
    const float* b_cw   = (const float*)d_in[12];
    const float* b_cb   = (const float*)d_in[13];
    const float* b_dtb  = (const float*)d_in[14];
    const float* b_Alog = (const float*)d_in[15];
    const float* b_D    = (const float*)d_in[16];
    const float* b_gn   = (const float*)d_in[17];
    const float* b_Wout = (const float*)d_in[18];

    float* out = (float*)d_out;
    char*  wsb = (char*)d_ws;
    // ws layout (bytes, total 251,265,024 = 239.6 MiB < R6's proven 253.4 MB):
    //   xbuf/Sbuf 67,108,864 | W1hi 7,274,496 | W1lo | W2hi 3,145,728 | W2lo |
    //   zs 85,983,232 | spb 6,291,456 | xrawT 67,108,864 | bnd 3,932,160
    float* xbuf = (float*)wsb;
    u16*   Sbuf = (u16*)wsb;                       // overlays xbuf (disjoint lifetimes)
    size_t off = 67108864;
    u16* W1hi = (u16*)(wsb + off); off += (size_t)12 * 74 * 4096 * 2;
    u16* W1lo = (u16*)(wsb + off); off += (size_t)12 * 74 * 4096 * 2;
    u16* W2hi = (u16*)(wsb + off); off += (size_t)12 * 16 * 8192 * 2;
    u16* W2lo = (u16*)(wsb + off); off += (size_t)12 * 16 * 8192 * 2;
    u16* zs   = (u16*)(wsb + off); off += (size_t)NTOK * ZW * 2;
    float* spb = (float*)(wsb + off); off += (size_t)NTOK * 24 * 4;
    u16* xrawT = (u16*)(wsb + off); off += (size_t)NTOK * 512 * 2;
    u16* bnd  = (u16*)(wsb + off);

    kprep_win<<<dim3(74, 12), 512, 0, stream>>>(t_Win, b_Win, W1hi, W1lo);
    kprep_wout<<<dim3(16, 12), 512, 0, stream>>>(t_Wout, t_gn, b_Wout, b_gn, W2hi, W2lo);

    for (int i = 0; i < NLAY; i++) {
        const float* src_t = (i == 0) ? x : out;
        // ---- time pass: 128 seqs x L=512, transposed store ----
        k1_mfma<<<NCH, 512, 0, stream>>>(src_t, zs, xrawT, bnd, t_norm + i * Hd,
                 W1hi + (size_t)i * 74 * 4096, W1lo + (size_t)i * 74 * 4096);
        k2a_conv<<<NCH, 256, 0, stream>>>(zs, xrawT, spb, bnd,
                 t_cw + i * 4 * CONVDv, t_cb + i * CONVDv, t_dtb + i * NHEADS,
                 t_Alog + i * NHEADS, 512);
        k2b_ssd<true><<<NCH, 256, 0, stream>>>(zs, xrawT, spb, Sbuf, t_D + i * NHEADS);
        k2c_states<<<dim3(128, NHEADS), 64, 0, stream>>>(Sbuf, spb);
        k2d_corr<<<NCH, 256, 0, stream>>>(zs, xrawT, spb, Sbuf);
        k3_mfma<true><<<NTOK/128, 512, 0, stream>>>(zs, src_t, xbuf,
                 W2hi + (size_t)i * 16 * 8192, W2lo + (size_t)i * 16 * 8192);
        // ---- band pass: 1024 seqs x L=64 (single chunk), identity store ----
        k1_mfma<<<NCH, 512, 0, stream>>>(xbuf, zs, xrawT, bnd, b_norm + i * Hd,
                 W1hi + (size_t)(i + 6) * 74 * 4096, W1lo + (size_t)(i + 6) * 74 * 4096);
        k2a_conv<<<NCH, 256, 0, stream>>>(zs, xrawT, spb, bnd,
                 b_cw + i * 4 * CONVDv, b_cb + i * CONVDv, b_dtb + i * NHEADS,
                 b_Alog + i * NHEADS, 64);
        k2b_ssd<false><<<NCH, 256, 0, stream>>>(zs, xrawT, spb, Sbuf, b_D + i * NHEADS);
        k3_mfma<false><<<NTOK/128, 512, 0, stream>>>(zs, xbuf, out,
                 W2hi + (size_t)(i + 6) * 16 * 8192, W2lo + (size_t)(i + 6) * 16 * 8192);
    }
}